// Round 11
// baseline (307.452 us; speedup 1.0000x reference)
//
#include <hip/hip_runtime.h>
#include <hip/hip_bf16.h>

// Problem: B=2, S=2048, DIM=1536, H=12, HD=128
//   q = rope(rms(x@wq.T + bq, gq)); k likewise; v = x@wv.T + bv
//   attn per head, out = attn_out @ wo.T + bo   (all fp32 reference)
// Strategy: bf16 MFMA pipeline (threshold = 2% of ref max, plenty of headroom).

#define BQ  2
#define SQ  2048
#define DIMQ 1536
#define HQ  12
#define HDQ 128
#define MTOK 4096          // B*S
#define KDIM 1536

typedef __attribute__((ext_vector_type(8))) short short8;   // 8 x bf16 (4 VGPR)
typedef __attribute__((ext_vector_type(4))) float f32x4;
typedef __attribute__((ext_vector_type(16))) float f32x16;
typedef __attribute__((ext_vector_type(8))) unsigned short u16x8;

typedef __attribute__((address_space(1))) const void global_cvoid;
typedef __attribute__((address_space(3))) void lds_void;

__device__ const float CEc = 0.12751879f;    // (1/sqrt(128)) * log2(e)

__device__ __forceinline__ float bf2f(unsigned int u) {
    return __uint_as_float(u << 16);
}
__device__ __forceinline__ unsigned short f2bf(float f) {
    unsigned int u = __float_as_uint(f);
    u += 0x7fffu + ((u >> 16) & 1u);   // round-to-nearest-even
    return (unsigned short)(u >> 16);
}
__device__ __forceinline__ void gload_lds16(const void* g, void* l) {
    __builtin_amdgcn_global_load_lds((global_cvoid*)g, (lds_void*)l, 16, 0, 0);
}
__device__ __forceinline__ unsigned int cvtpk_bf16(float lo, float hi) {
    unsigned int r;
    asm("v_cvt_pk_bf16_f32 %0, %1, %2" : "=v"(r) : "v"(lo), "v"(hi));
    return r;
}

// counted vmcnt wait (T4): never drain to 0 in the main loop
#define VMCNT(n) asm volatile("s_waitcnt vmcnt(" #n ")" ::: "memory")
#define MEMFENCE() asm volatile("" ::: "memory")

// ---------------------------------------------------------------- fused casts f32->bf16
__global__ __launch_bounds__(256)
void cast_all(const float* __restrict__ x,
              const float* __restrict__ wq, const float* __restrict__ wk,
              const float* __restrict__ wv, const float* __restrict__ wo,
              unsigned short* __restrict__ Xb,
              unsigned short* __restrict__ Wqkv,
              unsigned short* __restrict__ Wob)
{
    const int NX = 1572864, NW = 589824;
    int i = blockIdx.x * blockDim.x + threadIdx.x;
    int stride = gridDim.x * blockDim.x;
    for (; i < NX + 4 * NW; i += stride) {
        const float* s; unsigned short* d; int off;
        if (i < NX) { s = x; d = Xb; off = i; }
        else {
            int j = i - NX;
            int seg = j / NW;
            off = j - seg * NW;
            s = (seg == 0) ? wq : (seg == 1) ? wk : (seg == 2) ? wv : wo;
            d = (seg < 3) ? (Wqkv + seg * 2359296) : Wob;
        }
        float4 v = ((const float4*)s)[off];
        unsigned short a = f2bf(v.x), b = f2bf(v.y), c = f2bf(v.z), e = f2bf(v.w);
        unsigned int lo = (unsigned int)a | ((unsigned int)b << 16);
        unsigned int hi = (unsigned int)c | ((unsigned int)e << 16);
        ((uint2*)d)[off] = make_uint2(lo, hi);
    }
}

// ---------------------------------------------------------------- GEMM C = A * B^T  (+bias)
template<int MODE>
__global__ __launch_bounds__(256)
void gemm_bt(const unsigned short* __restrict__ A,
             const unsigned short* __restrict__ Bm,
             unsigned short* __restrict__ oQ,
             unsigned short* __restrict__ oK,
             unsigned short* __restrict__ oV,
             const float* __restrict__ biasq,
             const float* __restrict__ biask,
             const float* __restrict__ biasv,
             float* __restrict__ oF,
             const float* __restrict__ biaso)
{
    __shared__ unsigned short ldsA[128 * 64];   // 16 KB
    __shared__ unsigned short ldsB[128 * 64];   // 16 KB
    const int m0 = blockIdx.x * 128;
    const int n0 = blockIdx.y * 128;
    const int t = threadIdx.x;
    const int lane = t & 63;
    const int wid = t >> 6;
    const int wr = (wid >> 1) * 64;
    const int wc = (wid & 1) * 64;
    const int lr = lane & 15;
    const int lk = lane >> 4;

    f32x4 acc[4][4] = {};

    #pragma unroll 1
    for (int kt = 0; kt < KDIM; kt += 64) {
        #pragma unroll
        for (int i = 0; i < 4; ++i) {
            const int off = i * 4096 + wid * 1024 + lane * 16;  // byte offset in tile
            const int r = off >> 7;
            const int c = (off >> 4) & 7;
            const int csw = (c ^ (r & 7)) << 3;                 // element offset in row
            gload_lds16(A + (size_t)(m0 + r) * KDIM + kt + csw,
                        (char*)ldsA + i * 4096 + wid * 1024);
            gload_lds16(Bm + (size_t)(n0 + r) * KDIM + kt + csw,
                        (char*)ldsB + i * 4096 + wid * 1024);
        }
        __syncthreads();

        #pragma unroll
        for (int kk = 0; kk < 2; ++kk) {
            short8 af[4], bf[4];
            #pragma unroll
            for (int mi = 0; mi < 4; ++mi) {
                int row = wr + mi * 16 + lr;
                int ch = (kk * 4 + lk) ^ (row & 7);
                af[mi] = *(const short8*)((const char*)ldsA + row * 128 + ch * 16);
            }
            #pragma unroll
            for (int ni = 0; ni < 4; ++ni) {
                int row = wc + ni * 16 + lr;
                int ch = (kk * 4 + lk) ^ (row & 7);
                bf[ni] = *(const short8*)((const char*)ldsB + row * 128 + ch * 16);
            }
            #pragma unroll
            for (int mi = 0; mi < 4; ++mi)
                #pragma unroll
                for (int ni = 0; ni < 4; ++ni)
                    acc[mi][ni] = __builtin_amdgcn_mfma_f32_16x16x32_bf16(
                        af[mi], bf[ni], acc[mi][ni], 0, 0, 0);
        }
        __syncthreads();
    }

    // epilogue: D layout col=lane&15, row=(lane>>4)*4+j  [m89-verified]
    if (MODE == 0) {
        const int seg = n0 / 1536;
        unsigned short* op = (seg == 0) ? oQ : (seg == 1 ? oK : oV);
        const float* bp = (seg == 0) ? biasq : (seg == 1 ? biask : biasv);
        const int nl0 = n0 - seg * 1536;
        #pragma unroll
        for (int mi = 0; mi < 4; ++mi)
            #pragma unroll
            for (int ni = 0; ni < 4; ++ni)
                #pragma unroll
                for (int j = 0; j < 4; ++j) {
                    int row = m0 + wr + mi * 16 + lk * 4 + j;
                    int col = nl0 + wc + ni * 16 + lr;
                    op[(size_t)row * 1536 + col] = f2bf(acc[mi][ni][j] + bp[col]);
                }
    } else {
        #pragma unroll
        for (int mi = 0; mi < 4; ++mi)
            #pragma unroll
            for (int ni = 0; ni < 4; ++ni)
                #pragma unroll
                for (int j = 0; j < 4; ++j) {
                    int row = m0 + wr + mi * 16 + lk * 4 + j;
                    int col = n0 + wc + ni * 16 + lr;
                    oF[(size_t)row * 1536 + col] = acc[mi][ni][j] + biaso[col];
                }
    }
}

// ---------------------------------------------------------------- RMSNorm (full row) + RoPE, in place
// grid (4096, 2): y=0 -> (Q, gq), y=1 -> (K, gk)
__global__ __launch_bounds__(256)
void rmsnorm_rope(unsigned short* __restrict__ Qb,
                  unsigned short* __restrict__ Kb,
                  const float* __restrict__ gq,
                  const float* __restrict__ gk,
                  const float* __restrict__ freqs)
{
    unsigned short* T = blockIdx.y ? Kb : Qb;
    const float* g = blockIdx.y ? gk : gq;
    const int token = blockIdx.x;          // 0..4095
    const int s = token & (SQ - 1);
    unsigned int* row = (unsigned int*)(T + (size_t)token * DIMQ);
    const int t = threadIdx.x;
    const int lane = t & 63, wid = t >> 6;

    float pr[3], pi[3];
    float ss = 0.f;
    #pragma unroll
    for (int q = 0; q < 3; ++q) {
        unsigned int v = row[t + q * 256];
        float a = bf2f(v & 0xffffu);
        float b = bf2f(v >> 16);
        pr[q] = a; pi[q] = b;
        ss += a * a + b * b;
    }
    ss += __shfl_xor(ss, 32); ss += __shfl_xor(ss, 16); ss += __shfl_xor(ss, 8);
    ss += __shfl_xor(ss, 4);  ss += __shfl_xor(ss, 2);  ss += __shfl_xor(ss, 1);
    __shared__ float red[4];
    if (lane == 0) red[wid] = ss;
    __syncthreads();
    float tot = red[0] + red[1] + red[2] + red[3];
    float sc = rsqrtf(tot * (1.0f / 1536.0f) + 1e-6f);

    #pragma unroll
    for (int q = 0; q < 3; ++q) {
        int p = t + q * 256;               // global pair index 0..767
        int ph = p & 63;                   // pair-in-head
        float fr = freqs[s * 128 + ph * 2];
        float fi = freqs[s * 128 + ph * 2 + 1];
        float nr = pr[q] * sc * g[2 * p];
        float ni = pi[q] * sc * g[2 * p + 1];
        float outr = nr * fr - ni * fi;
        float outi = nr * fi + ni * fr;
        row[p] = (unsigned int)f2bf(outr) | ((unsigned int)f2bf(outi) << 16);
    }
}

// ---------------------------------------------------------------- V transpose: [B,S,H,HD] -> [B*H, HD, S]
__global__ __launch_bounds__(256)
void vtrans(const unsigned short* __restrict__ V, unsigned short* __restrict__ Vt)
{
    __shared__ unsigned short tile[64][72];   // +8 pad
    const int s0 = blockIdx.x * 64;
    const int d0 = blockIdx.y * 64;
    const int bh = blockIdx.z;
    const int b = bh / HQ, h = bh % HQ;
    const int t = threadIdx.x;

    #pragma unroll
    for (int i = 0; i < 2; ++i) {
        int cid = i * 256 + t;
        int r = cid >> 3, c = cid & 7;
        u16x8 v = *(const u16x8*)(V + (size_t)(b * SQ + s0 + r) * DIMQ + h * HDQ + d0 + c * 8);
        #pragma unroll
        for (int e = 0; e < 8; ++e) tile[r][c * 8 + e] = v[e];
    }
    __syncthreads();
    #pragma unroll
    for (int i = 0; i < 2; ++i) {
        int cid = i * 256 + t;
        int rd = cid >> 3, c = cid & 7;
        u16x8 w;
        #pragma unroll
        for (int e = 0; e < 8; ++e) w[e] = tile[c * 8 + e][rd];
        *(u16x8*)(Vt + (size_t)(bh * HDQ + d0 + rd) * SQ + s0 + c * 8) = w;
    }
}

// ---------------------------------------------------------------- flash attention
// 1 wave per block (64 threads), 32 q-rows, KVBLK=32, NO barriers (wave-private LDS).
// K double-buffered (2x8KB DMA) + V single (8KB, issued early); two counted vmcnts
// per iter (T4). Swapped QK^T = mfma(K,Q), lane-local online softmax, P via
// cvt_pk + shfl_xor(32) + select, PV computes O^T = mfma(V^T, P^T).
// Grid 1536 = 6 blocks/CU exactly; LDS 24KB -> 6 resident.
// R11 deltas vs R5 (proven base): cross-half lsum deferred to epilogue (proven
// R7-R9); T5 setprio around MFMA clusters (m191 attn regime: independent waves).
__global__ __launch_bounds__(64)
void attn(const unsigned short* __restrict__ Q,
          const unsigned short* __restrict__ Kb,
          const unsigned short* __restrict__ Vt,
          unsigned short* __restrict__ Ao)
{
    __shared__ char smem[24576];
    char* Kl0 = smem;            // [32 kv][128 k] bf16, 256B rows, XOR-swizzled chunks
    char* Kl1 = smem + 8192;
    char* Vl  = smem + 16384;    // [128 d][32 kv] bf16, 64B rows, XOR-swizzled

    // XCD remap: 8 XCDs x 3 heads x 64 q-blocks (3MB K/V per XCD fits its L2)
    const int fid = blockIdx.x;             // 0..1535
    const int xcd = fid & 7;
    const int slot = fid >> 3;              // 0..191
    const int bh = xcd * 3 + (slot >> 6);   // 0..23
    const int sblk = slot & 63;
    const int b = bh / HQ, h = bh % HQ;
    const int s0 = sblk * 32;

    const int lane = threadIdx.x;
    const int l31 = lane & 31, hi = lane >> 5;
    const float THR = 90.5f;                // defer-max threshold, raw-score units

    const unsigned short* Kbase = Kb + (size_t)(b * SQ) * DIMQ + h * HDQ;
    const unsigned short* Vbase = Vt + (size_t)(bh * HDQ) * SQ;

    // Q fragments (B-operand: col q = l31, k = kc*16 + hi*8 + e)
    short8 qf[8];
    {
        const unsigned short* qp = Q + (size_t)(b * SQ + s0 + l31) * DIMQ + h * HDQ;
        #pragma unroll
        for (int kc = 0; kc < 8; ++kc)
            qf[kc] = *(const short8*)(qp + kc * 16 + hi * 8);
    }
    MEMFENCE();                 // keep Q loads before the first DMA
    // prologue: K(0) -> Kl0
    #pragma unroll
    for (int i = 0; i < 8; ++i) {
        const int off = i * 1024 + lane * 16;
        int r = off >> 8, c = (off >> 4) & 15;
        gload_lds16(Kbase + (size_t)r * DIMQ + ((c ^ (r & 7)) << 3), Kl0 + i * 1024);
    }
    VMCNT(8);                   // Q settled; K(0)'s 8 DMAs in flight

    char* kcur = Kl0;
    char* knxt = Kl1;
    float mrun = -1e30f, lsum = 0.f, nm = 1e30f;   // nm = -mrun*CE
    f32x16 oacc[4] = {};        // O^T: col q = l31, row d = dt*32 + crow(r,hi)

    #pragma unroll 1
    for (int kv0 = 0; kv0 < SQ; kv0 += 32) {
        // issue V(t): [128 d][32 kv], rows 64B = 4 chunks; swz c ^ ((r>>1)&3)
        #pragma unroll
        for (int i = 0; i < 8; ++i) {
            const int off = i * 1024 + lane * 16;
            int r = off >> 6, c = (off >> 4) & 3;
            gload_lds16(Vbase + (size_t)r * SQ + kv0 + ((c ^ ((r >> 1) & 3)) << 3),
                        Vl + i * 1024);
        }
        MEMFENCE();
        // issue K(t+1) (clamped in-bounds on last iter; dup write never read)
        const int kvn = (kv0 + 32 < SQ) ? kv0 + 32 : kv0;
        #pragma unroll
        for (int i = 0; i < 8; ++i) {
            const int off = i * 1024 + lane * 16;
            int r = off >> 8, c = (off >> 4) & 15;
            gload_lds16(Kbase + (size_t)(kvn + r) * DIMQ + ((c ^ (r & 7)) << 3),
                        knxt + i * 1024);
        }

        VMCNT(16);              // K(t) landed; V(t)+K(t+1) still in flight

        // ---- S^T = K * Q^T, two independent 4-chains
        f32x16 sa = {}, sb = {};
        const int rb = l31 * 256;
        const int rx = l31 & 7;
        __builtin_amdgcn_s_setprio(1);
        #pragma unroll
        for (int kc = 0; kc < 4; ++kc) {
            short8 kf = *(const short8*)(kcur + rb + (((kc * 2 + hi) ^ rx) << 4));
            sa = __builtin_amdgcn_mfma_f32_32x32x16_bf16(kf, qf[kc], sa, 0, 0, 0);
        }
        #pragma unroll
        for (int kc = 4; kc < 8; ++kc) {
            short8 kf = *(const short8*)(kcur + rb + (((kc * 2 + hi) ^ rx) << 4));
            sb = __builtin_amdgcn_mfma_f32_32x32x16_bf16(kf, qf[kc], sb, 0, 0, 0);
        }
        __builtin_amdgcn_s_setprio(0);
        f32x16 s;
        #pragma unroll
        for (int r = 0; r < 16; ++r) s[r] = sa[r] + sb[r];

        // ---- online softmax (lane-local; partner lane^32 holds the other 16 kv)
        float mt[8];
        #pragma unroll
        for (int r = 0; r < 8; ++r) mt[r] = fmaxf(s[r], s[r + 8]);
        #pragma unroll
        for (int st = 4; st > 0; st >>= 1)
            #pragma unroll
            for (int r = 0; r < 4; ++r)
                if (r < st) mt[r] = fmaxf(mt[r], mt[r + st]);
        float tm = fmaxf(mt[0], __shfl_xor(mt[0], 32));
        if (!__all(tm <= mrun + THR)) {     // defer-max (T13)
            float mnew = fmaxf(mrun, tm);
            float al = __builtin_amdgcn_exp2f((mrun - mnew) * CEc);
            lsum *= al;
            #pragma unroll
            for (int dt = 0; dt < 4; ++dt)
                #pragma unroll
                for (int r = 0; r < 16; ++r) oacc[dt][r] *= al;
            mrun = mnew;
            nm = -mrun * CEc;
        }
        float rs = 0.f;
        #pragma unroll
        for (int r = 0; r < 16; ++r) {
            float p = __builtin_amdgcn_exp2f(__builtin_fmaf(s[r], CEc, nm));
            s[r] = p; rs += p;
        }
        lsum += rs;             // half-local; cross-half sum deferred to epilogue
                                // (valid: mrun is identical for lane pairs l/l^32
                                // since tm is cross-half-synced before each update)

        // ---- P -> bf16 B-frags (kv = ks*16 + hi*8 + e per word pair)
        unsigned int A0 = cvtpk_bf16(s[0], s[1]),  A1 = cvtpk_bf16(s[2], s[3]);
        unsigned int B0 = cvtpk_bf16(s[4], s[5]),  B1 = cvtpk_bf16(s[6], s[7]);
        unsigned int C0 = cvtpk_bf16(s[8], s[9]),  C1 = cvtpk_bf16(s[10], s[11]);
        unsigned int D0 = cvtpk_bf16(s[12], s[13]), D1 = cvtpk_bf16(s[14], s[15]);
        unsigned int xA0 = __shfl_xor(A0, 32), xA1 = __shfl_xor(A1, 32);
        unsigned int xB0 = __shfl_xor(B0, 32), xB1 = __shfl_xor(B1, 32);
        unsigned int xC0 = __shfl_xor(C0, 32), xC1 = __shfl_xor(C1, 32);
        unsigned int xD0 = __shfl_xor(D0, 32), xD1 = __shfl_xor(D1, 32);
        union { unsigned int w[4]; short8 v; } pf0, pf1;
        pf0.w[0] = hi ? xB0 : A0;  pf0.w[1] = hi ? xB1 : A1;
        pf0.w[2] = hi ? B0 : xA0;  pf0.w[3] = hi ? B1 : xA1;
        pf1.w[0] = hi ? xD0 : C0;  pf1.w[1] = hi ? xD1 : C1;
        pf1.w[2] = hi ? D0 : xC0;  pf1.w[3] = hi ? D1 : xC1;

        VMCNT(8);               // V(t) landed; K(t+1) still in flight

        // ---- O^T += V^T P^T  (4 independent 2-chains)
        __builtin_amdgcn_s_setprio(1);
        #pragma unroll
        for (int dt = 0; dt < 4; ++dt) {
            const int drow = dt * 32 + l31;
            const int sw = (drow >> 1) & 3;
            short8 v0 = *(const short8*)(Vl + drow * 64 + ((hi ^ sw) << 4));
            short8 v1 = *(const short8*)(Vl + drow * 64 + (((2 + hi) ^ sw) << 4));
            oacc[dt] = __builtin_amdgcn_mfma_f32_32x32x16_bf16(v0, pf0.v, oacc[dt], 0, 0, 0);
            oacc[dt] = __builtin_amdgcn_mfma_f32_32x32x16_bf16(v1, pf1.v, oacc[dt], 0, 0, 0);
        }
        __builtin_amdgcn_s_setprio(0);

        char* tp = kcur; kcur = knxt; knxt = tp;
    }

    // ---- epilogue: cross-half lsum, normalize, transpose O^T -> O via wave-private
    // swizzled LDS (V region; only K-prefetch DMA is in flight, targets K buffers)
    float ltot = lsum + __shfl_xor(lsum, 32);
    const float rls = 1.0f / ltot;
    char* Ot = Vl;              // [32 q][128 d] bf16, 256B rows, XOR-swizzled
    #pragma unroll
    for (int dt = 0; dt < 4; ++dt)
        #pragma unroll
        for (int rp = 0; rp < 8; ++rp) {
            const int r = 2 * rp;
            float v0 = oacc[dt][r] * rls;
            float v1 = oacc[dt][r + 1] * rls;
            int d = dt * 32 + (r & 3) + 8 * (r >> 2) + 4 * hi;   // even
            unsigned int w = (unsigned int)f2bf(v0) | ((unsigned int)f2bf(v1) << 16);
            int addr = l31 * 256 + (((d >> 3) ^ (l31 & 7)) << 4) + (d & 7) * 2;
            *(unsigned int*)(Ot + addr) = w;
        }
    #pragma unroll
    for (int ii = 0; ii < 8; ++ii) {
        int task = ii * 64 + lane;          // 32 q x 16 chunks
        int q = task >> 4, c = task & 15;
        u16x8 vv = *(const u16x8*)(Ot + q * 256 + ((c ^ (q & 7)) << 4));
        int tok = b * SQ + s0 + q;
        *(u16x8*)(Ao + (size_t)tok * DIMQ + h * HDQ + c * 8) = vv;
    }
}

// ---------------------------------------------------------------- launch
extern "C" void kernel_launch(void* const* d_in, const int* in_sizes, int n_in,
                              void* d_out, int out_size, void* d_ws, size_t ws_size,
                              hipStream_t stream) {
    (void)in_sizes; (void)n_in; (void)out_size; (void)ws_size;
    const float* x     = (const float*)d_in[0];
    const float* freqs = (const float*)d_in[1];
    const float* wq = (const float*)d_in[2];
    const float* bq = (const float*)d_in[3];
    const float* wk = (const float*)d_in[4];
    const float* bk = (const float*)d_in[5];
    const float* wv = (const float*)d_in[6];
    const float* bv = (const float*)d_in[7];
    const float* wo = (const float*)d_in[8];
    const float* bo = (const float*)d_in[9];
    const float* gq = (const float*)d_in[10];
    const float* gk = (const float*)d_in[11];
    float* out = (float*)d_out;

    char* w = (char*)d_ws;
    unsigned short* Xb   = (unsigned short*)(w);               // 4096x1536 bf16
    unsigned short* Wqkv = (unsigned short*)(w + 12582912);    // 4608x1536 bf16
    unsigned short* Wob  = (unsigned short*)(w + 26738688);    // 1536x1536 bf16
    unsigned short* Qb   = (unsigned short*)(w + 31457280);    // 4096x1536 bf16
    unsigned short* Kbuf = (unsigned short*)(w + 44040192);    // 4096x1536 bf16
    unsigned short* Vb   = (unsigned short*)(w + 56623104);    // 4096x1536 bf16
    unsigned short* Vt   = (unsigned short*)(w + 69206016);    // 24x128x2048 bf16
    unsigned short* Ao   = Xb;   // Xb dead after GEMM1 -> reuse for attention out

    cast_all<<<2048, 256, 0, stream>>>(x, wq, wk, wv, wo, Xb, Wqkv, Wob);

    gemm_bt<0><<<dim3(32, 36), 256, 0, stream>>>(
        Xb, Wqkv, Qb, Kbuf, Vb, bq, bk, bv, nullptr, nullptr);

    rmsnorm_rope<<<dim3(4096, 2), 256, 0, stream>>>(Qb, Kbuf, gq, gk, freqs);
    vtrans<<<dim3(32, 2, 24), 256, 0, stream>>>(Vb, Vt);

    attn<<<1536, 64, 0, stream>>>(Qb, Kbuf, Vt, Ao);

    gemm_bt<1><<<dim3(32, 12), 256, 0, stream>>>(
        Ao, Wob, nullptr, nullptr, nullptr, nullptr, nullptr, nullptr, out, bo);
}

// Round 12
// 253.581 us; speedup vs baseline: 1.2124x; 1.2124x over previous
//
#include <hip/hip_runtime.h>
#include <hip/hip_bf16.h>

// Problem: B=2, S=2048, DIM=1536, H=12, HD=128
//   q = rope(rms(x@wq.T + bq, gq)); k likewise; v = x@wv.T + bv
//   attn per head, out = attn_out @ wo.T + bo   (all fp32 reference)
// Strategy: bf16 MFMA pipeline (threshold = 2% of ref max, plenty of headroom).

#define BQ  2
#define SQ  2048
#define DIMQ 1536
#define HQ  12
#define HDQ 128
#define MTOK 4096          // B*S
#define KDIM 1536

typedef __attribute__((ext_vector_type(8))) short short8;   // 8 x bf16 (4 VGPR)
typedef __attribute__((ext_vector_type(4))) float f32x4;
typedef __attribute__((ext_vector_type(16))) float f32x16;
typedef __attribute__((ext_vector_type(8))) unsigned short u16x8;

typedef __attribute__((address_space(1))) const void global_cvoid;
typedef __attribute__((address_space(3))) void lds_void;

__device__ __forceinline__ float bf2f(unsigned int u) {
    return __uint_as_float(u << 16);
}
__device__ __forceinline__ unsigned short f2bf(float f) {
    unsigned int u = __float_as_uint(f);
    u += 0x7fffu + ((u >> 16) & 1u);   // round-to-nearest-even
    return (unsigned short)(u >> 16);
}
__device__ __forceinline__ void gload_lds16(const void* g, void* l) {
    __builtin_amdgcn_global_load_lds((global_cvoid*)g, (lds_void*)l, 16, 0, 0);
}
__device__ __forceinline__ unsigned int cvtpk_bf16(float lo, float hi) {
    unsigned int r;
    asm("v_cvt_pk_bf16_f32 %0, %1, %2" : "=v"(r) : "v"(lo), "v"(hi));
    return r;
}

// counted vmcnt wait (T4): never drain to 0 in the main loop
#define VMCNT(n) asm volatile("s_waitcnt vmcnt(" #n ")" ::: "memory")
#define MEMFENCE() asm volatile("" ::: "memory")

// ---------------------------------------------------------------- fused casts f32->bf16
__global__ __launch_bounds__(256)
void cast_all(const float* __restrict__ x,
              const float* __restrict__ wq, const float* __restrict__ wk,
              const float* __restrict__ wv, const float* __restrict__ wo,
              unsigned short* __restrict__ Xb,
              unsigned short* __restrict__ Wqkv,
              unsigned short* __restrict__ Wob)
{
    const int NX = 1572864, NW = 589824;
    int i = blockIdx.x * blockDim.x + threadIdx.x;
    int stride = gridDim.x * blockDim.x;
    for (; i < NX + 4 * NW; i += stride) {
        const float* s; unsigned short* d; int off;
        if (i < NX) { s = x; d = Xb; off = i; }
        else {
            int j = i - NX;
            int seg = j / NW;
            off = j - seg * NW;
            s = (seg == 0) ? wq : (seg == 1) ? wk : (seg == 2) ? wv : wo;
            d = (seg < 3) ? (Wqkv + seg * 2359296) : Wob;
        }
        float4 v = ((const float4*)s)[off];
        unsigned short a = f2bf(v.x), b = f2bf(v.y), c = f2bf(v.z), e = f2bf(v.w);
        unsigned int lo = (unsigned int)a | ((unsigned int)b << 16);
        unsigned int hi = (unsigned int)c | ((unsigned int)e << 16);
        ((uint2*)d)[off] = make_uint2(lo, hi);
    }
}

// ---------------------------------------------------------------- GEMM C = A * B^T  (+bias)
template<int MODE>
__global__ __launch_bounds__(256)
void gemm_bt(const unsigned short* __restrict__ A,
             const unsigned short* __restrict__ Bm,
             unsigned short* __restrict__ oQ,
             unsigned short* __restrict__ oK,
             unsigned short* __restrict__ oV,
             const float* __restrict__ biasq,
             const float* __restrict__ biask,
             const float* __restrict__ biasv,
             float* __restrict__ oF,
             const float* __restrict__ biaso)
{
    __shared__ unsigned short ldsA[128 * 64];   // 16 KB
    __shared__ unsigned short ldsB[128 * 64];   // 16 KB
    const int m0 = blockIdx.x * 128;
    const int n0 = blockIdx.y * 128;
    const int t = threadIdx.x;
    const int lane = t & 63;
    const int wid = t >> 6;
    const int wr = (wid >> 1) * 64;
    const int wc = (wid & 1) * 64;
    const int lr = lane & 15;
    const int lk = lane >> 4;

    f32x4 acc[4][4] = {};

    #pragma unroll 1
    for (int kt = 0; kt < KDIM; kt += 64) {
        #pragma unroll
        for (int i = 0; i < 4; ++i) {
            const int off = i * 4096 + wid * 1024 + lane * 16;  // byte offset in tile
            const int r = off >> 7;
            const int c = (off >> 4) & 7;
            const int csw = (c ^ (r & 7)) << 3;                 // element offset in row
            gload_lds16(A + (size_t)(m0 + r) * KDIM + kt + csw,
                        (char*)ldsA + i * 4096 + wid * 1024);
            gload_lds16(Bm + (size_t)(n0 + r) * KDIM + kt + csw,
                        (char*)ldsB + i * 4096 + wid * 1024);
        }
        __syncthreads();

        #pragma unroll
        for (int kk = 0; kk < 2; ++kk) {
            short8 af[4], bf[4];
            #pragma unroll
            for (int mi = 0; mi < 4; ++mi) {
                int row = wr + mi * 16 + lr;
                int ch = (kk * 4 + lk) ^ (row & 7);
                af[mi] = *(const short8*)((const char*)ldsA + row * 128 + ch * 16);
            }
            #pragma unroll
            for (int ni = 0; ni < 4; ++ni) {
                int row = wc + ni * 16 + lr;
                int ch = (kk * 4 + lk) ^ (row & 7);
                bf[ni] = *(const short8*)((const char*)ldsB + row * 128 + ch * 16);
            }
            #pragma unroll
            for (int mi = 0; mi < 4; ++mi)
                #pragma unroll
                for (int ni = 0; ni < 4; ++ni)
                    acc[mi][ni] = __builtin_amdgcn_mfma_f32_16x16x32_bf16(
                        af[mi], bf[ni], acc[mi][ni], 0, 0, 0);
        }
        __syncthreads();
    }

    // epilogue: D layout col=lane&15, row=(lane>>4)*4+j  [m89-verified]
    if (MODE == 0) {
        const int seg = n0 / 1536;
        unsigned short* op = (seg == 0) ? oQ : (seg == 1 ? oK : oV);
        const float* bp = (seg == 0) ? biasq : (seg == 1 ? biask : biasv);
        const int nl0 = n0 - seg * 1536;
        #pragma unroll
        for (int mi = 0; mi < 4; ++mi)
            #pragma unroll
            for (int ni = 0; ni < 4; ++ni)
                #pragma unroll
                for (int j = 0; j < 4; ++j) {
                    int row = m0 + wr + mi * 16 + lk * 4 + j;
                    int col = nl0 + wc + ni * 16 + lr;
                    op[(size_t)row * 1536 + col] = f2bf(acc[mi][ni][j] + bp[col]);
                }
    } else {
        #pragma unroll
        for (int mi = 0; mi < 4; ++mi)
            #pragma unroll
            for (int ni = 0; ni < 4; ++ni)
                #pragma unroll
                for (int j = 0; j < 4; ++j) {
                    int row = m0 + wr + mi * 16 + lk * 4 + j;
                    int col = n0 + wc + ni * 16 + lr;
                    oF[(size_t)row * 1536 + col] = acc[mi][ni][j] + biaso[col];
                }
    }
}

// ---------------------------------------------------------------- RMSNorm (full row) + RoPE, in place
// grid (4096, 2): y=0 -> (Q, gq), y=1 -> (K, gk)
__global__ __launch_bounds__(256)
void rmsnorm_rope(unsigned short* __restrict__ Qb,
                  unsigned short* __restrict__ Kb,
                  const float* __restrict__ gq,
                  const float* __restrict__ gk,
                  const float* __restrict__ freqs)
{
    unsigned short* T = blockIdx.y ? Kb : Qb;
    const float* g = blockIdx.y ? gk : gq;
    const int token = blockIdx.x;          // 0..4095
    const int s = token & (SQ - 1);
    unsigned int* row = (unsigned int*)(T + (size_t)token * DIMQ);
    const int t = threadIdx.x;
    const int lane = t & 63, wid = t >> 6;

    float pr[3], pi[3];
    float ss = 0.f;
    #pragma unroll
    for (int q = 0; q < 3; ++q) {
        unsigned int v = row[t + q * 256];
        float a = bf2f(v & 0xffffu);
        float b = bf2f(v >> 16);
        pr[q] = a; pi[q] = b;
        ss += a * a + b * b;
    }
    ss += __shfl_xor(ss, 32); ss += __shfl_xor(ss, 16); ss += __shfl_xor(ss, 8);
    ss += __shfl_xor(ss, 4);  ss += __shfl_xor(ss, 2);  ss += __shfl_xor(ss, 1);
    __shared__ float red[4];
    if (lane == 0) red[wid] = ss;
    __syncthreads();
    float tot = red[0] + red[1] + red[2] + red[3];
    float sc = rsqrtf(tot * (1.0f / 1536.0f) + 1e-6f);

    #pragma unroll
    for (int q = 0; q < 3; ++q) {
        int p = t + q * 256;               // global pair index 0..767
        int ph = p & 63;                   // pair-in-head
        float fr = freqs[s * 128 + ph * 2];
        float fi = freqs[s * 128 + ph * 2 + 1];
        float nr = pr[q] * sc * g[2 * p];
        float ni = pi[q] * sc * g[2 * p + 1];
        float outr = nr * fr - ni * fi;
        float outi = nr * fi + ni * fr;
        row[p] = (unsigned int)f2bf(outr) | ((unsigned int)f2bf(outi) << 16);
    }
}

// ---------------------------------------------------------------- V transpose: [B,S,H,HD] -> [B*H, HD, S]
__global__ __launch_bounds__(256)
void vtrans(const unsigned short* __restrict__ V, unsigned short* __restrict__ Vt)
{
    __shared__ unsigned short tile[64][72];   // +8 pad
    const int s0 = blockIdx.x * 64;
    const int d0 = blockIdx.y * 64;
    const int bh = blockIdx.z;
    const int b = bh / HQ, h = bh % HQ;
    const int t = threadIdx.x;

    #pragma unroll
    for (int i = 0; i < 2; ++i) {
        int cid = i * 256 + t;
        int r = cid >> 3, c = cid & 7;
        u16x8 v = *(const u16x8*)(V + (size_t)(b * SQ + s0 + r) * DIMQ + h * HDQ + d0 + c * 8);
        #pragma unroll
        for (int e = 0; e < 8; ++e) tile[r][c * 8 + e] = v[e];
    }
    __syncthreads();
    #pragma unroll
    for (int i = 0; i < 2; ++i) {
        int cid = i * 256 + t;
        int rd = cid >> 3, c = cid & 7;
        u16x8 w;
        #pragma unroll
        for (int e = 0; e < 8; ++e) w[e] = tile[c * 8 + e][rd];
        *(u16x8*)(Vt + (size_t)(bh * HDQ + d0 + rd) * SQ + s0 + c * 8) = w;
    }
}

// ---------------------------------------------------------------- flash attention
// EXACT R5 kernel (measured 121.3 us, 104 VGPR, passed): 1 wave per block,
// 32 q-rows, KVBLK=32, NO barriers (wave-private LDS). K double-buffered
// (2x8KB DMA) + V single (8KB, issued early); two counted vmcnts per iter (T4).
// Swapped QK^T = mfma(K,Q), lane-local online softmax, P via cvt_pk +
// shfl_xor(32) + select, PV computes O^T = mfma(V^T, P^T).
// Grid 1536 = 6 blocks/CU exactly; LDS 24KB -> 6 resident.
// NOTE (R11 post-mortem): adding s_setprio around the MFMA clusters bloated
// VGPR 104->140 and halved occupancy -> attn 121->180 us. Do not re-add.
__global__ __launch_bounds__(64, 2)
void attn(const unsigned short* __restrict__ Q,
          const unsigned short* __restrict__ Kb,
          const unsigned short* __restrict__ Vt,
          unsigned short* __restrict__ Ao)
{
    __shared__ char smem[24576];
    char* Kl0 = smem;            // [32 kv][128 k] bf16, 256B rows, XOR-swizzled chunks
    char* Kl1 = smem + 8192;
    char* Vl  = smem + 16384;    // [128 d][32 kv] bf16, 64B rows, XOR-swizzled

    // XCD remap: 8 XCDs x 3 heads x 64 q-blocks (3MB K/V per XCD fits its L2)
    const int fid = blockIdx.x;             // 0..1535
    const int xcd = fid & 7;
    const int slot = fid >> 3;              // 0..191
    const int bh = xcd * 3 + (slot >> 6);   // 0..23
    const int sblk = slot & 63;
    const int b = bh / HQ, h = bh % HQ;
    const int s0 = sblk * 32;

    const int lane = threadIdx.x;
    const int l31 = lane & 31, hi = lane >> 5;
    const float CE = 0.12751879f;           // (1/sqrt(128)) * log2(e)
    const float THR = 90.5f;                // defer-max threshold, raw-score units

    const unsigned short* Kbase = Kb + (size_t)(b * SQ) * DIMQ + h * HDQ;
    const unsigned short* Vbase = Vt + (size_t)(bh * HDQ) * SQ;

    // Q fragments (B-operand: col q = l31, k = kc*16 + hi*8 + e)
    short8 qf[8];
    {
        const unsigned short* qp = Q + (size_t)(b * SQ + s0 + l31) * DIMQ + h * HDQ;
        #pragma unroll
        for (int kc = 0; kc < 8; ++kc)
            qf[kc] = *(const short8*)(qp + kc * 16 + hi * 8);
    }
    MEMFENCE();                 // keep Q loads before the first DMA
    // prologue: K(0) -> Kl0
    #pragma unroll
    for (int i = 0; i < 8; ++i) {
        const int off = i * 1024 + lane * 16;
        int r = off >> 8, c = (off >> 4) & 15;
        gload_lds16(Kbase + (size_t)r * DIMQ + ((c ^ (r & 7)) << 3), Kl0 + i * 1024);
    }
    VMCNT(8);                   // Q settled; K(0)'s 8 DMAs in flight

    char* kcur = Kl0;
    char* knxt = Kl1;
    float mrun = -1e30f, lsum = 0.f, nm = 1e30f;   // nm = -mrun*CE
    f32x16 oacc[4] = {};        // O^T: col q = l31, row d = dt*32 + crow(r,hi)

    #pragma unroll 1
    for (int kv0 = 0; kv0 < SQ; kv0 += 32) {
        // issue V(t): [128 d][32 kv], rows 64B = 4 chunks; swz c ^ ((r>>1)&3)
        #pragma unroll
        for (int i = 0; i < 8; ++i) {
            const int off = i * 1024 + lane * 16;
            int r = off >> 6, c = (off >> 4) & 3;
            gload_lds16(Vbase + (size_t)r * SQ + kv0 + ((c ^ ((r >> 1) & 3)) << 3),
                        Vl + i * 1024);
        }
        MEMFENCE();
        // issue K(t+1) (clamped in-bounds on last iter; dup write never read)
        const int kvn = (kv0 + 32 < SQ) ? kv0 + 32 : kv0;
        #pragma unroll
        for (int i = 0; i < 8; ++i) {
            const int off = i * 1024 + lane * 16;
            int r = off >> 8, c = (off >> 4) & 15;
            gload_lds16(Kbase + (size_t)(kvn + r) * DIMQ + ((c ^ (r & 7)) << 3),
                        knxt + i * 1024);
        }

        VMCNT(16);              // K(t) landed; V(t)+K(t+1) still in flight

        // ---- S^T = K * Q^T, two independent 4-chains
        f32x16 sa = {}, sb = {};
        const int rb = l31 * 256;
        const int rx = l31 & 7;
        #pragma unroll
        for (int kc = 0; kc < 4; ++kc) {
            short8 kf = *(const short8*)(kcur + rb + (((kc * 2 + hi) ^ rx) << 4));
            sa = __builtin_amdgcn_mfma_f32_32x32x16_bf16(kf, qf[kc], sa, 0, 0, 0);
        }
        #pragma unroll
        for (int kc = 4; kc < 8; ++kc) {
            short8 kf = *(const short8*)(kcur + rb + (((kc * 2 + hi) ^ rx) << 4));
            sb = __builtin_amdgcn_mfma_f32_32x32x16_bf16(kf, qf[kc], sb, 0, 0, 0);
        }
        f32x16 s;
        #pragma unroll
        for (int r = 0; r < 16; ++r) s[r] = sa[r] + sb[r];

        // ---- online softmax (lane-local; partner lane^32 holds the other 16 kv)
        float mt[8];
        #pragma unroll
        for (int r = 0; r < 8; ++r) mt[r] = fmaxf(s[r], s[r + 8]);
        #pragma unroll
        for (int st = 4; st > 0; st >>= 1)
            #pragma unroll
            for (int r = 0; r < 4; ++r)
                if (r < st) mt[r] = fmaxf(mt[r], mt[r + st]);
        float tm = fmaxf(mt[0], __shfl_xor(mt[0], 32));
        if (!__all(tm <= mrun + THR)) {     // defer-max (T13)
            float mnew = fmaxf(mrun, tm);
            float al = __builtin_amdgcn_exp2f((mrun - mnew) * CE);
            lsum *= al;
            #pragma unroll
            for (int dt = 0; dt < 4; ++dt)
                #pragma unroll
                for (int r = 0; r < 16; ++r) oacc[dt][r] *= al;
            mrun = mnew;
            nm = -mrun * CE;
        }
        float rs = 0.f;
        #pragma unroll
        for (int r = 0; r < 16; ++r) {
            float p = __builtin_amdgcn_exp2f(__builtin_fmaf(s[r], CE, nm));
            s[r] = p; rs += p;
        }
        rs += __shfl_xor(rs, 32);
        lsum += rs;

        // ---- P -> bf16 B-frags (kv = ks*16 + hi*8 + e per word pair)
        unsigned int A0 = cvtpk_bf16(s[0], s[1]),  A1 = cvtpk_bf16(s[2], s[3]);
        unsigned int B0 = cvtpk_bf16(s[4], s[5]),  B1 = cvtpk_bf16(s[6], s[7]);
        unsigned int C0 = cvtpk_bf16(s[8], s[9]),  C1 = cvtpk_bf16(s[10], s[11]);
        unsigned int D0 = cvtpk_bf16(s[12], s[13]), D1 = cvtpk_bf16(s[14], s[15]);
        unsigned int xA0 = __shfl_xor(A0, 32), xA1 = __shfl_xor(A1, 32);
        unsigned int xB0 = __shfl_xor(B0, 32), xB1 = __shfl_xor(B1, 32);
        unsigned int xC0 = __shfl_xor(C0, 32), xC1 = __shfl_xor(C1, 32);
        unsigned int xD0 = __shfl_xor(D0, 32), xD1 = __shfl_xor(D1, 32);
        union { unsigned int w[4]; short8 v; } pf0, pf1;
        pf0.w[0] = hi ? xB0 : A0;  pf0.w[1] = hi ? xB1 : A1;
        pf0.w[2] = hi ? B0 : xA0;  pf0.w[3] = hi ? B1 : xA1;
        pf1.w[0] = hi ? xD0 : C0;  pf1.w[1] = hi ? xD1 : C1;
        pf1.w[2] = hi ? D0 : xC0;  pf1.w[3] = hi ? D1 : xC1;

        VMCNT(8);               // V(t) landed; K(t+1) still in flight

        // ---- O^T += V^T P^T  (4 independent 2-chains)
        #pragma unroll
        for (int dt = 0; dt < 4; ++dt) {
            const int drow = dt * 32 + l31;
            const int sw = (drow >> 1) & 3;
            short8 v0 = *(const short8*)(Vl + drow * 64 + ((hi ^ sw) << 4));
            short8 v1 = *(const short8*)(Vl + drow * 64 + (((2 + hi) ^ sw) << 4));
            oacc[dt] = __builtin_amdgcn_mfma_f32_32x32x16_bf16(v0, pf0.v, oacc[dt], 0, 0, 0);
            oacc[dt] = __builtin_amdgcn_mfma_f32_32x32x16_bf16(v1, pf1.v, oacc[dt], 0, 0, 0);
        }

        char* tp = kcur; kcur = knxt; knxt = tp;
    }

    // ---- epilogue: normalize, transpose O^T -> O via wave-private swizzled LDS
    // (V region; only K-prefetch DMA is in flight and it targets the K buffers)
    const float rls = 1.0f / lsum;
    char* Ot = Vl;              // [32 q][128 d] bf16, 256B rows, XOR-swizzled
    #pragma unroll
    for (int dt = 0; dt < 4; ++dt)
        #pragma unroll
        for (int rp = 0; rp < 8; ++rp) {
            const int r = 2 * rp;
            float v0 = oacc[dt][r] * rls;
            float v1 = oacc[dt][r + 1] * rls;
            int d = dt * 32 + (r & 3) + 8 * (r >> 2) + 4 * hi;   // even
            unsigned int w = (unsigned int)f2bf(v0) | ((unsigned int)f2bf(v1) << 16);
            int addr = l31 * 256 + (((d >> 3) ^ (l31 & 7)) << 4) + (d & 7) * 2;
            *(unsigned int*)(Ot + addr) = w;
        }
    #pragma unroll
    for (int ii = 0; ii < 8; ++ii) {
        int task = ii * 64 + lane;          // 32 q x 16 chunks
        int q = task >> 4, c = task & 15;
        u16x8 vv = *(const u16x8*)(Ot + q * 256 + ((c ^ (q & 7)) << 4));
        int tok = b * SQ + s0 + q;
        *(u16x8*)(Ao + (size_t)tok * DIMQ + h * HDQ + c * 8) = vv;
    }
}

// ---------------------------------------------------------------- launch
extern "C" void kernel_launch(void* const* d_in, const int* in_sizes, int n_in,
                              void* d_out, int out_size, void* d_ws, size_t ws_size,
                              hipStream_t stream) {
    (void)in_sizes; (void)n_in; (void)out_size; (void)ws_size;
    const float* x     = (const float*)d_in[0];
    const float* freqs = (const float*)d_in[1];
    const float* wq = (const float*)d_in[2];
    const float* bq = (const float*)d_in[3];
    const float* wk = (const float*)d_in[4];
    const float* bk = (const float*)d_in[5];
    const float* wv = (const float*)d_in[6];
    const float* bv = (const float*)d_in[7];
    const float* wo = (const float*)d_in[8];
    const float* bo = (const float*)d_in[9];
    const float* gq = (const float*)d_in[10];
    const float* gk = (const float*)d_in[11];
    float* out = (float*)d_out;

    char* w = (char*)d_ws;
    unsigned short* Xb   = (unsigned short*)(w);               // 4096x1536 bf16
    unsigned short* Wqkv = (unsigned short*)(w + 12582912);    // 4608x1536 bf16
    unsigned short* Wob  = (unsigned short*)(w + 26738688);    // 1536x1536 bf16
    unsigned short* Qb   = (unsigned short*)(w + 31457280);    // 4096x1536 bf16
    unsigned short* Kbuf = (unsigned short*)(w + 44040192);    // 4096x1536 bf16
    unsigned short* Vb   = (unsigned short*)(w + 56623104);    // 4096x1536 bf16
    unsigned short* Vt   = (unsigned short*)(w + 69206016);    // 24x128x2048 bf16
    unsigned short* Ao   = Xb;   // Xb dead after GEMM1 -> reuse for attention out

    cast_all<<<2048, 256, 0, stream>>>(x, wq, wk, wv, wo, Xb, Wqkv, Wob);

    gemm_bt<0><<<dim3(32, 36), 256, 0, stream>>>(
        Xb, Wqkv, Qb, Kbuf, Vb, bq, bk, bv, nullptr, nullptr);

    rmsnorm_rope<<<dim3(4096, 2), 256, 0, stream>>>(Qb, Kbuf, gq, gk, freqs);
    vtrans<<<dim3(32, 2, 24), 256, 0, stream>>>(Vb, Vt);

    attn<<<1536, 64, 0, stream>>>(Qb, Kbuf, Vt, Ao);

    gemm_bt<1><<<dim3(32, 12), 256, 0, stream>>>(
        Ao, Wob, nullptr, nullptr, nullptr, nullptr, nullptr, nullptr, out, bo);
}

// Round 13
// 245.609 us; speedup vs baseline: 1.2518x; 1.0325x over previous
//
#include <hip/hip_runtime.h>
#include <hip/hip_bf16.h>

// Problem: B=2, S=2048, DIM=1536, H=12, HD=128
//   q = rope(rms(x@wq.T + bq, gq)); k likewise; v = x@wv.T + bv
//   attn per head, out = attn_out @ wo.T + bo   (all fp32 reference)
// Strategy: bf16 MFMA pipeline (threshold = 2% of ref max, plenty of headroom).

#define BQ  2
#define SQ  2048
#define DIMQ 1536
#define HQ  12
#define HDQ 128
#define MTOK 4096          // B*S
#define KDIM 1536

typedef __attribute__((ext_vector_type(8))) short short8;   // 8 x bf16 (4 VGPR)
typedef __attribute__((ext_vector_type(4))) float f32x4;
typedef __attribute__((ext_vector_type(16))) float f32x16;
typedef __attribute__((ext_vector_type(8))) unsigned short u16x8;

typedef __attribute__((address_space(1))) const void global_cvoid;
typedef __attribute__((address_space(3))) void lds_void;

__device__ __forceinline__ float bf2f(unsigned int u) {
    return __uint_as_float(u << 16);
}
__device__ __forceinline__ unsigned short f2bf(float f) {
    unsigned int u = __float_as_uint(f);
    u += 0x7fffu + ((u >> 16) & 1u);   // round-to-nearest-even
    return (unsigned short)(u >> 16);
}
__device__ __forceinline__ void gload_lds16(const void* g, void* l) {
    __builtin_amdgcn_global_load_lds((global_cvoid*)g, (lds_void*)l, 16, 0, 0);
}
__device__ __forceinline__ unsigned int cvtpk_bf16(float lo, float hi) {
    unsigned int r;
    asm("v_cvt_pk_bf16_f32 %0, %1, %2" : "=v"(r) : "v"(lo), "v"(hi));
    return r;
}

// counted vmcnt wait (T4): never drain to 0 in the main loop
#define VMCNT(n) asm volatile("s_waitcnt vmcnt(" #n ")" ::: "memory")
#define MEMFENCE() asm volatile("" ::: "memory")
// raw barrier: compiler fences only, no vmcnt/lgkmcnt drain (unlike __syncthreads)
#define BARRIER() do { asm volatile("" ::: "memory"); \
                       __builtin_amdgcn_s_barrier();  \
                       asm volatile("" ::: "memory"); } while (0)

// ---------------------------------------------------------------- fused casts f32->bf16
__global__ __launch_bounds__(256)
void cast_all(const float* __restrict__ x,
              const float* __restrict__ wq, const float* __restrict__ wk,
              const float* __restrict__ wv, const float* __restrict__ wo,
              unsigned short* __restrict__ Xb,
              unsigned short* __restrict__ Wqkv,
              unsigned short* __restrict__ Wob)
{
    const int NX = 1572864, NW = 589824;
    int i = blockIdx.x * blockDim.x + threadIdx.x;
    int stride = gridDim.x * blockDim.x;
    for (; i < NX + 4 * NW; i += stride) {
        const float* s; unsigned short* d; int off;
        if (i < NX) { s = x; d = Xb; off = i; }
        else {
            int j = i - NX;
            int seg = j / NW;
            off = j - seg * NW;
            s = (seg == 0) ? wq : (seg == 1) ? wk : (seg == 2) ? wv : wo;
            d = (seg < 3) ? (Wqkv + seg * 2359296) : Wob;
        }
        float4 v = ((const float4*)s)[off];
        unsigned short a = f2bf(v.x), b = f2bf(v.y), c = f2bf(v.z), e = f2bf(v.w);
        unsigned int lo = (unsigned int)a | ((unsigned int)b << 16);
        unsigned int hi = (unsigned int)c | ((unsigned int)e << 16);
        ((uint2*)d)[off] = make_uint2(lo, hi);
    }
}

// ---------------------------------------------------------------- GEMM C = A * B^T  (+bias)
// 128x128 tile, 4 waves (2x2 of 64x64). R13: BK=32 double-buffered (2x8KB A +
// 2x8KB B = 32KB LDS, occupancy unchanged at 5 blocks/CU) with the T3/T4
// counted-prefetch schedule proven in this session's attn kernel:
//   stage(t+1) -> VMCNT(4) [own stage(t) retired; stage(t+1) stays in flight
//   across both raw barriers] -> barrier -> compute(t) -> barrier.
// No vmcnt(0) drain in the loop (the ~20% __syncthreads stall of the old form).
// Rows are 64B = 4 chunks; XOR swizzle chunk ^ (row&3) on both DMA source and read.
template<int MODE>
__global__ __launch_bounds__(256)
void gemm_bt(const unsigned short* __restrict__ A,
             const unsigned short* __restrict__ Bm,
             unsigned short* __restrict__ oQ,
             unsigned short* __restrict__ oK,
             unsigned short* __restrict__ oV,
             const float* __restrict__ biasq,
             const float* __restrict__ biask,
             const float* __restrict__ biasv,
             float* __restrict__ oF,
             const float* __restrict__ biaso)
{
    __shared__ unsigned short ldsA[2][128 * 32];   // 8 KB per buffer
    __shared__ unsigned short ldsB[2][128 * 32];
    const int m0 = blockIdx.x * 128;
    const int n0 = blockIdx.y * 128;
    const int t = threadIdx.x;
    const int lane = t & 63;
    const int wid = t >> 6;
    const int wr = (wid >> 1) * 64;
    const int wc = (wid & 1) * 64;
    const int lr = lane & 15;
    const int lk = lane >> 4;

    f32x4 acc[4][4] = {};

    // prologue: stage K-step 0 into buf 0
    #pragma unroll
    for (int i = 0; i < 2; ++i) {
        const int off = i * 4096 + wid * 1024 + lane * 16;   // byte offset in 8KB tile
        const int r = off >> 6;
        const int c = (off >> 4) & 3;
        const int csw = (c ^ (r & 3)) << 3;
        gload_lds16(A + (size_t)(m0 + r) * KDIM + csw,
                    (char*)ldsA[0] + i * 4096 + wid * 1024);
        gload_lds16(Bm + (size_t)(n0 + r) * KDIM + csw,
                    (char*)ldsB[0] + i * 4096 + wid * 1024);
    }

    #pragma unroll 1
    for (int s = 0; s < KDIM / 32; ++s) {
        const int cb = s & 1;
        if (s + 1 < KDIM / 32) {
            // stage(t+1) into the buffer freed by step s-1 (post-barrier of s-1)
            const int kt = (s + 1) * 32;
            #pragma unroll
            for (int i = 0; i < 2; ++i) {
                const int off = i * 4096 + wid * 1024 + lane * 16;
                const int r = off >> 6;
                const int c = (off >> 4) & 3;
                const int csw = (c ^ (r & 3)) << 3;
                gload_lds16(A + (size_t)(m0 + r) * KDIM + kt + csw,
                            (char*)ldsA[cb ^ 1] + i * 4096 + wid * 1024);
                gload_lds16(Bm + (size_t)(n0 + r) * KDIM + kt + csw,
                            (char*)ldsB[cb ^ 1] + i * 4096 + wid * 1024);
            }
            VMCNT(4);           // own stage(s) retired; stage(s+1)'s 4 in flight
        } else {
            VMCNT(0);           // last step: drain everything
        }
        BARRIER();              // all waves' stage(s) visible

        short8 af[4], bf[4];
        #pragma unroll
        for (int mi = 0; mi < 4; ++mi) {
            int row = wr + mi * 16 + lr;
            int ch = lk ^ (row & 3);
            af[mi] = *(const short8*)((const char*)ldsA[cb] + row * 64 + ch * 16);
        }
        #pragma unroll
        for (int ni = 0; ni < 4; ++ni) {
            int row = wc + ni * 16 + lr;
            int ch = lk ^ (row & 3);
            bf[ni] = *(const short8*)((const char*)ldsB[cb] + row * 64 + ch * 16);
        }
        #pragma unroll
        for (int mi = 0; mi < 4; ++mi)
            #pragma unroll
            for (int ni = 0; ni < 4; ++ni)
                acc[mi][ni] = __builtin_amdgcn_mfma_f32_16x16x32_bf16(
                    af[mi], bf[ni], acc[mi][ni], 0, 0, 0);

        BARRIER();              // all waves done reading buf[cb] -> may be overwritten
    }

    // epilogue: D layout col=lane&15, row=(lane>>4)*4+j  [m89-verified]
    if (MODE == 0) {
        const int seg = n0 / 1536;
        unsigned short* op = (seg == 0) ? oQ : (seg == 1 ? oK : oV);
        const float* bp = (seg == 0) ? biasq : (seg == 1 ? biask : biasv);
        const int nl0 = n0 - seg * 1536;
        #pragma unroll
        for (int mi = 0; mi < 4; ++mi)
            #pragma unroll
            for (int ni = 0; ni < 4; ++ni)
                #pragma unroll
                for (int j = 0; j < 4; ++j) {
                    int row = m0 + wr + mi * 16 + lk * 4 + j;
                    int col = nl0 + wc + ni * 16 + lr;
                    op[(size_t)row * 1536 + col] = f2bf(acc[mi][ni][j] + bp[col]);
                }
    } else {
        #pragma unroll
        for (int mi = 0; mi < 4; ++mi)
            #pragma unroll
            for (int ni = 0; ni < 4; ++ni)
                #pragma unroll
                for (int j = 0; j < 4; ++j) {
                    int row = m0 + wr + mi * 16 + lk * 4 + j;
                    int col = n0 + wc + ni * 16 + lr;
                    oF[(size_t)row * 1536 + col] = acc[mi][ni][j] + biaso[col];
                }
    }
}

// ---------------------------------------------------------------- RMSNorm (full row) + RoPE, in place
// grid (4096, 2): y=0 -> (Q, gq), y=1 -> (K, gk)
__global__ __launch_bounds__(256)
void rmsnorm_rope(unsigned short* __restrict__ Qb,
                  unsigned short* __restrict__ Kb,
                  const float* __restrict__ gq,
                  const float* __restrict__ gk,
                  const float* __restrict__ freqs)
{
    unsigned short* T = blockIdx.y ? Kb : Qb;
    const float* g = blockIdx.y ? gk : gq;
    const int token = blockIdx.x;          // 0..4095
    const int s = token & (SQ - 1);
    unsigned int* row = (unsigned int*)(T + (size_t)token * DIMQ);
    const int t = threadIdx.x;
    const int lane = t & 63, wid = t >> 6;

    float pr[3], pi[3];
    float ss = 0.f;
    #pragma unroll
    for (int q = 0; q < 3; ++q) {
        unsigned int v = row[t + q * 256];
        float a = bf2f(v & 0xffffu);
        float b = bf2f(v >> 16);
        pr[q] = a; pi[q] = b;
        ss += a * a + b * b;
    }
    ss += __shfl_xor(ss, 32); ss += __shfl_xor(ss, 16); ss += __shfl_xor(ss, 8);
    ss += __shfl_xor(ss, 4);  ss += __shfl_xor(ss, 2);  ss += __shfl_xor(ss, 1);
    __shared__ float red[4];
    if (lane == 0) red[wid] = ss;
    __syncthreads();
    float tot = red[0] + red[1] + red[2] + red[3];
    float sc = rsqrtf(tot * (1.0f / 1536.0f) + 1e-6f);

    #pragma unroll
    for (int q = 0; q < 3; ++q) {
        int p = t + q * 256;               // global pair index 0..767
        int ph = p & 63;                   // pair-in-head
        float fr = freqs[s * 128 + ph * 2];
        float fi = freqs[s * 128 + ph * 2 + 1];
        float nr = pr[q] * sc * g[2 * p];
        float ni = pi[q] * sc * g[2 * p + 1];
        float outr = nr * fr - ni * fi;
        float outi = nr * fi + ni * fr;
        row[p] = (unsigned int)f2bf(outr) | ((unsigned int)f2bf(outi) << 16);
    }
}

// ---------------------------------------------------------------- V transpose: [B,S,H,HD] -> [B*H, HD, S]
__global__ __launch_bounds__(256)
void vtrans(const unsigned short* __restrict__ V, unsigned short* __restrict__ Vt)
{
    __shared__ unsigned short tile[64][72];   // +8 pad
    const int s0 = blockIdx.x * 64;
    const int d0 = blockIdx.y * 64;
    const int bh = blockIdx.z;
    const int b = bh / HQ, h = bh % HQ;
    const int t = threadIdx.x;

    #pragma unroll
    for (int i = 0; i < 2; ++i) {
        int cid = i * 256 + t;
        int r = cid >> 3, c = cid & 7;
        u16x8 v = *(const u16x8*)(V + (size_t)(b * SQ + s0 + r) * DIMQ + h * HDQ + d0 + c * 8);
        #pragma unroll
        for (int e = 0; e < 8; ++e) tile[r][c * 8 + e] = v[e];
    }
    __syncthreads();
    #pragma unroll
    for (int i = 0; i < 2; ++i) {
        int cid = i * 256 + t;
        int rd = cid >> 3, c = cid & 7;
        u16x8 w;
        #pragma unroll
        for (int e = 0; e < 8; ++e) w[e] = tile[c * 8 + e][rd];
        *(u16x8*)(Vt + (size_t)(bh * HDQ + d0 + rd) * SQ + s0 + c * 8) = w;
    }
}

// ---------------------------------------------------------------- flash attention
// EXACT R5 kernel (measured 121.3 us, 104 VGPR, passed): 1 wave per block,
// 32 q-rows, KVBLK=32, NO barriers (wave-private LDS). K double-buffered
// (2x8KB DMA) + V single (8KB, issued early); two counted vmcnts per iter (T4).
// Swapped QK^T = mfma(K,Q), lane-local online softmax, P via cvt_pk +
// shfl_xor(32) + select, PV computes O^T = mfma(V^T, P^T).
// Grid 1536 = 6 blocks/CU exactly; LDS 24KB -> 6 resident.
// NOTE (R11 post-mortem): adding s_setprio around the MFMA clusters bloated
// VGPR 104->140 and halved occupancy -> attn 121->180 us. Do not re-add.
__global__ __launch_bounds__(64, 2)
void attn(const unsigned short* __restrict__ Q,
          const unsigned short* __restrict__ Kb,
          const unsigned short* __restrict__ Vt,
          unsigned short* __restrict__ Ao)
{
    __shared__ char smem[24576];
    char* Kl0 = smem;            // [32 kv][128 k] bf16, 256B rows, XOR-swizzled chunks
    char* Kl1 = smem + 8192;
    char* Vl  = smem + 16384;    // [128 d][32 kv] bf16, 64B rows, XOR-swizzled

    // XCD remap: 8 XCDs x 3 heads x 64 q-blocks (3MB K/V per XCD fits its L2)
    const int fid = blockIdx.x;             // 0..1535
    const int xcd = fid & 7;
    const int slot = fid >> 3;              // 0..191
    const int bh = xcd * 3 + (slot >> 6);   // 0..23
    const int sblk = slot & 63;
    const int b = bh / HQ, h = bh % HQ;
    const int s0 = sblk * 32;

    const int lane = threadIdx.x;
    const int l31 = lane & 31, hi = lane >> 5;
    const float CE = 0.12751879f;           // (1/sqrt(128)) * log2(e)
    const float THR = 90.5f;                // defer-max threshold, raw-score units

    const unsigned short* Kbase = Kb + (size_t)(b * SQ) * DIMQ + h * HDQ;
    const unsigned short* Vbase = Vt + (size_t)(bh * HDQ) * SQ;

    // Q fragments (B-operand: col q = l31, k = kc*16 + hi*8 + e)
    short8 qf[8];
    {
        const unsigned short* qp = Q + (size_t)(b * SQ + s0 + l31) * DIMQ + h * HDQ;
        #pragma unroll
        for (int kc = 0; kc < 8; ++kc)
            qf[kc] = *(const short8*)(qp + kc * 16 + hi * 8);
    }
    MEMFENCE();                 // keep Q loads before the first DMA
    // prologue: K(0) -> Kl0
    #pragma unroll
    for (int i = 0; i < 8; ++i) {
        const int off = i * 1024 + lane * 16;
        int r = off >> 8, c = (off >> 4) & 15;
        gload_lds16(Kbase + (size_t)r * DIMQ + ((c ^ (r & 7)) << 3), Kl0 + i * 1024);
    }
    VMCNT(8);                   // Q settled; K(0)'s 8 DMAs in flight

    char* kcur = Kl0;
    char* knxt = Kl1;
    float mrun = -1e30f, lsum = 0.f, nm = 1e30f;   // nm = -mrun*CE
    f32x16 oacc[4] = {};        // O^T: col q = l31, row d = dt*32 + crow(r,hi)

    #pragma unroll 1
    for (int kv0 = 0; kv0 < SQ; kv0 += 32) {
        // issue V(t): [128 d][32 kv], rows 64B = 4 chunks; swz c ^ ((r>>1)&3)
        #pragma unroll
        for (int i = 0; i < 8; ++i) {
            const int off = i * 1024 + lane * 16;
            int r = off >> 6, c = (off >> 4) & 3;
            gload_lds16(Vbase + (size_t)r * SQ + kv0 + ((c ^ ((r >> 1) & 3)) << 3),
                        Vl + i * 1024);
        }
        MEMFENCE();
        // issue K(t+1) (clamped in-bounds on last iter; dup write never read)
        const int kvn = (kv0 + 32 < SQ) ? kv0 + 32 : kv0;
        #pragma unroll
        for (int i = 0; i < 8; ++i) {
            const int off = i * 1024 + lane * 16;
            int r = off >> 8, c = (off >> 4) & 15;
            gload_lds16(Kbase + (size_t)(kvn + r) * DIMQ + ((c ^ (r & 7)) << 3),
                        knxt + i * 1024);
        }

        VMCNT(16);              // K(t) landed; V(t)+K(t+1) still in flight

        // ---- S^T = K * Q^T, two independent 4-chains
        f32x16 sa = {}, sb = {};
        const int rb = l31 * 256;
        const int rx = l31 & 7;
        #pragma unroll
        for (int kc = 0; kc < 4; ++kc) {
            short8 kf = *(const short8*)(kcur + rb + (((kc * 2 + hi) ^ rx) << 4));
            sa = __builtin_amdgcn_mfma_f32_32x32x16_bf16(kf, qf[kc], sa, 0, 0, 0);
        }
        #pragma unroll
        for (int kc = 4; kc < 8; ++kc) {
            short8 kf = *(const short8*)(kcur + rb + (((kc * 2 + hi) ^ rx) << 4));
            sb = __builtin_amdgcn_mfma_f32_32x32x16_bf16(kf, qf[kc], sb, 0, 0, 0);
        }
        f32x16 s;
        #pragma unroll
        for (int r = 0; r < 16; ++r) s[r] = sa[r] + sb[r];

        // ---- online softmax (lane-local; partner lane^32 holds the other 16 kv)
        float mt[8];
        #pragma unroll
        for (int r = 0; r < 8; ++r) mt[r] = fmaxf(s[r], s[r + 8]);
        #pragma unroll
        for (int st = 4; st > 0; st >>= 1)
            #pragma unroll
            for (int r = 0; r < 4; ++r)
                if (r < st) mt[r] = fmaxf(mt[r], mt[r + st]);
        float tm = fmaxf(mt[0], __shfl_xor(mt[0], 32));
        if (!__all(tm <= mrun + THR)) {     // defer-max (T13)
            float mnew = fmaxf(mrun, tm);
            float al = __builtin_amdgcn_exp2f((mrun - mnew) * CE);
            lsum *= al;
            #pragma unroll
            for (int dt = 0; dt < 4; ++dt)
                #pragma unroll
                for (int r = 0; r < 16; ++r) oacc[dt][r] *= al;
            mrun = mnew;
            nm = -mrun * CE;
        }
        float rs = 0.f;
        #pragma unroll
        for (int r = 0; r < 16; ++r) {
            float p = __builtin_amdgcn_exp2f(__builtin_fmaf(s[r], CE, nm));
            s[r] = p; rs += p;
        }
        rs += __shfl_xor(rs, 32);
        lsum += rs;

        // ---- P -> bf16 B-frags (kv = ks*16 + hi*8 + e per word pair)
        unsigned int A0 = cvtpk_bf16(s[0], s[1]),  A1 = cvtpk_bf16(s[2], s[3]);
        unsigned int B0 = cvtpk_bf16(s[4], s[5]),  B1 = cvtpk_bf16(s[6], s[7]);
        unsigned int C0 = cvtpk_bf16(s[8], s[9]),  C1 = cvtpk_bf16(s[10], s[11]);
        unsigned int D0 = cvtpk_bf16(s[12], s[13]), D1 = cvtpk_bf16(s[14], s[15]);
        unsigned int xA0 = __shfl_xor(A0, 32), xA1 = __shfl_xor(A1, 32);
        unsigned int xB0 = __shfl_xor(B0, 32), xB1 = __shfl_xor(B1, 32);
        unsigned int xC0 = __shfl_xor(C0, 32), xC1 = __shfl_xor(C1, 32);
        unsigned int xD0 = __shfl_xor(D0, 32), xD1 = __shfl_xor(D1, 32);
        union { unsigned int w[4]; short8 v; } pf0, pf1;
        pf0.w[0] = hi ? xB0 : A0;  pf0.w[1] = hi ? xB1 : A1;
        pf0.w[2] = hi ? B0 : xA0;  pf0.w[3] = hi ? B1 : xA1;
        pf1.w[0] = hi ? xD0 : C0;  pf1.w[1] = hi ? xD1 : C1;
        pf1.w[2] = hi ? D0 : xC0;  pf1.w[3] = hi ? D1 : xC1;

        VMCNT(8);               // V(t) landed; K(t+1) still in flight

        // ---- O^T += V^T P^T  (4 independent 2-chains)
        #pragma unroll
        for (int dt = 0; dt < 4; ++dt) {
            const int drow = dt * 32 + l31;
            const int sw = (drow >> 1) & 3;
            short8 v0 = *(const short8*)(Vl + drow * 64 + ((hi ^ sw) << 4));
            short8 v1 = *(const short8*)(Vl + drow * 64 + (((2 + hi) ^ sw) << 4));
            oacc[dt] = __builtin_amdgcn_mfma_f32_32x32x16_bf16(v0, pf0.v, oacc[dt], 0, 0, 0);
            oacc[dt] = __builtin_amdgcn_mfma_f32_32x32x16_bf16(v1, pf1.v, oacc[dt], 0, 0, 0);
        }

        char* tp = kcur; kcur = knxt; knxt = tp;
    }

    // ---- epilogue: normalize, transpose O^T -> O via wave-private swizzled LDS
    // (V region; only K-prefetch DMA is in flight and it targets the K buffers)
    const float rls = 1.0f / lsum;
    char* Ot = Vl;              // [32 q][128 d] bf16, 256B rows, XOR-swizzled
    #pragma unroll
    for (int dt = 0; dt < 4; ++dt)
        #pragma unroll
        for (int rp = 0; rp < 8; ++rp) {
            const int r = 2 * rp;
            float v0 = oacc[dt][r] * rls;
            float v1 = oacc[dt][r + 1] * rls;
            int d = dt * 32 + (r & 3) + 8 * (r >> 2) + 4 * hi;   // even
            unsigned int w = (unsigned int)f2bf(v0) | ((unsigned int)f2bf(v1) << 16);
            int addr = l31 * 256 + (((d >> 3) ^ (l31 & 7)) << 4) + (d & 7) * 2;
            *(unsigned int*)(Ot + addr) = w;
        }
    #pragma unroll
    for (int ii = 0; ii < 8; ++ii) {
        int task = ii * 64 + lane;          // 32 q x 16 chunks
        int q = task >> 4, c = task & 15;
        u16x8 vv = *(const u16x8*)(Ot + q * 256 + ((c ^ (q & 7)) << 4));
        int tok = b * SQ + s0 + q;
        *(u16x8*)(Ao + (size_t)tok * DIMQ + h * HDQ + c * 8) = vv;
    }
}

// ---------------------------------------------------------------- launch
extern "C" void kernel_launch(void* const* d_in, const int* in_sizes, int n_in,
                              void* d_out, int out_size, void* d_ws, size_t ws_size,
                              hipStream_t stream) {
    (void)in_sizes; (void)n_in; (void)out_size; (void)ws_size;
    const float* x     = (const float*)d_in[0];
    const float* freqs = (const float*)d_in[1];
    const float* wq = (const float*)d_in[2];
    const float* bq = (const float*)d_in[3];
    const float* wk = (const float*)d_in[4];
    const float* bk = (const float*)d_in[5];
    const float* wv = (const float*)d_in[6];
    const float* bv = (const float*)d_in[7];
    const float* wo = (const float*)d_in[8];
    const float* bo = (const float*)d_in[9];
    const float* gq = (const float*)d_in[10];
    const float* gk = (const float*)d_in[11];
    float* out = (float*)d_out;

    char* w = (char*)d_ws;
    unsigned short* Xb   = (unsigned short*)(w);               // 4096x1536 bf16
    unsigned short* Wqkv = (unsigned short*)(w + 12582912);    // 4608x1536 bf16
    unsigned short* Wob  = (unsigned short*)(w + 26738688);    // 1536x1536 bf16
    unsigned short* Qb   = (unsigned short*)(w + 31457280);    // 4096x1536 bf16
    unsigned short* Kbuf = (unsigned short*)(w + 44040192);    // 4096x1536 bf16
    unsigned short* Vb   = (unsigned short*)(w + 56623104);    // 4096x1536 bf16
    unsigned short* Vt   = (unsigned short*)(w + 69206016);    // 24x128x2048 bf16
    unsigned short* Ao   = Xb;   // Xb dead after GEMM1 -> reuse for attention out

    cast_all<<<2048, 256, 0, stream>>>(x, wq, wk, wv, wo, Xb, Wqkv, Wob);

    gemm_bt<0><<<dim3(32, 36), 256, 0, stream>>>(
        Xb, Wqkv, Qb, Kbuf, Vb, bq, bk, bv, nullptr, nullptr);

    rmsnorm_rope<<<dim3(4096, 2), 256, 0, stream>>>(Qb, Kbuf, gq, gk, freqs);
    vtrans<<<dim3(32, 2, 24), 256, 0, stream>>>(Vb, Vt);

    attn<<<1536, 64, 0, stream>>>(Qb, Kbuf, Vt, Ao);

    gemm_bt<1><<<dim3(32, 12), 256, 0, stream>>>(
        Ao, Wob, nullptr, nullptr, nullptr, nullptr, nullptr, nullptr, out, bo);
}

// Round 14
// 235.999 us; speedup vs baseline: 1.3028x; 1.0407x over previous
//
#include <hip/hip_runtime.h>
#include <hip/hip_bf16.h>

// Problem: B=2, S=2048, DIM=1536, H=12, HD=128
//   q = rope(rms(x@wq.T + bq, gq)); k likewise; v = x@wv.T + bv
//   attn per head, out = attn_out @ wo.T + bo   (all fp32 reference)
// Strategy: bf16 MFMA pipeline (threshold = 2% of ref max, plenty of headroom).

#define BQ  2
#define SQ  2048
#define DIMQ 1536
#define HQ  12
#define HDQ 128
#define MTOK 4096          // B*S
#define KDIM 1536

typedef __attribute__((ext_vector_type(8))) short short8;   // 8 x bf16 (4 VGPR)
typedef __attribute__((ext_vector_type(4))) float f32x4;
typedef __attribute__((ext_vector_type(16))) float f32x16;
typedef __attribute__((ext_vector_type(8))) unsigned short u16x8;

typedef __attribute__((address_space(1))) const void global_cvoid;
typedef __attribute__((address_space(3))) void lds_void;

__device__ __forceinline__ float bf2f(unsigned int u) {
    return __uint_as_float(u << 16);
}
__device__ __forceinline__ unsigned short f2bf(float f) {
    unsigned int u = __float_as_uint(f);
    u += 0x7fffu + ((u >> 16) & 1u);   // round-to-nearest-even
    return (unsigned short)(u >> 16);
}
__device__ __forceinline__ void gload_lds16(const void* g, void* l) {
    __builtin_amdgcn_global_load_lds((global_cvoid*)g, (lds_void*)l, 16, 0, 0);
}
__device__ __forceinline__ unsigned int cvtpk_bf16(float lo, float hi) {
    unsigned int r;
    asm("v_cvt_pk_bf16_f32 %0, %1, %2" : "=v"(r) : "v"(lo), "v"(hi));
    return r;
}

// counted vmcnt wait (T4): never drain to 0 in the main loop
#define VMCNT(n) asm volatile("s_waitcnt vmcnt(" #n ")" ::: "memory")
#define MEMFENCE() asm volatile("" ::: "memory")
// raw barrier: compiler fences only, no vmcnt/lgkmcnt drain (unlike __syncthreads)
#define BARRIER() do { asm volatile("" ::: "memory"); \
                       __builtin_amdgcn_s_barrier();  \
                       asm volatile("" ::: "memory"); } while (0)

// ---------------------------------------------------------------- fused casts f32->bf16
__global__ __launch_bounds__(256)
void cast_all(const float* __restrict__ x,
              const float* __restrict__ wq, const float* __restrict__ wk,
              const float* __restrict__ wv, const float* __restrict__ wo,
              unsigned short* __restrict__ Xb,
              unsigned short* __restrict__ Wqkv,
              unsigned short* __restrict__ Wob)
{
    const int NX = 1572864, NW = 589824;
    int i = blockIdx.x * blockDim.x + threadIdx.x;
    int stride = gridDim.x * blockDim.x;
    for (; i < NX + 4 * NW; i += stride) {
        const float* s; unsigned short* d; int off;
        if (i < NX) { s = x; d = Xb; off = i; }
        else {
            int j = i - NX;
            int seg = j / NW;
            off = j - seg * NW;
            s = (seg == 0) ? wq : (seg == 1) ? wk : (seg == 2) ? wv : wo;
            d = (seg < 3) ? (Wqkv + seg * 2359296) : Wob;
        }
        float4 v = ((const float4*)s)[off];
        unsigned short a = f2bf(v.x), b = f2bf(v.y), c = f2bf(v.z), e = f2bf(v.w);
        unsigned int lo = (unsigned int)a | ((unsigned int)b << 16);
        unsigned int hi = (unsigned int)c | ((unsigned int)e << 16);
        ((uint2*)d)[off] = make_uint2(lo, hi);
    }
}

// ---------------------------------------------------------------- GEMM C = A * B^T  (+bias)
// 128x128 tile, 4 waves (2x2 of 64x64). BK=32 double-buffered (32KB LDS) with the
// T3/T4 counted-prefetch schedule (R13, proven): stage(t+1) -> VMCNT(4) ->
// barrier -> compute(t) -> barrier; no vmcnt(0) drain in-loop.
// R14: for MODE 0 seg==2 (the V segment) the epilogue transposes the tile through
// the (now dead) 32KB staging LDS and stores directly into the attn-ready layout
// Vt[bh][d][s] - the separate vtrans kernel is deleted.
template<int MODE>
__global__ __launch_bounds__(256)
void gemm_bt(const unsigned short* __restrict__ A,
             const unsigned short* __restrict__ Bm,
             unsigned short* __restrict__ oQ,
             unsigned short* __restrict__ oK,
             unsigned short* __restrict__ oV,    // MODE 0: Vt [24][128][2048]
             const float* __restrict__ biasq,
             const float* __restrict__ biask,
             const float* __restrict__ biasv,
             float* __restrict__ oF,
             const float* __restrict__ biaso)
{
    __shared__ char smem[32768];        // [A buf0|A buf1|B buf0|B buf1] 8KB each
    const int m0 = blockIdx.x * 128;
    const int n0 = blockIdx.y * 128;
    const int t = threadIdx.x;
    const int lane = t & 63;
    const int wid = t >> 6;
    const int wr = (wid >> 1) * 64;
    const int wc = (wid & 1) * 64;
    const int lr = lane & 15;
    const int lk = lane >> 4;

    f32x4 acc[4][4] = {};

    // prologue: stage K-step 0 into buf 0
    #pragma unroll
    for (int i = 0; i < 2; ++i) {
        const int off = i * 4096 + wid * 1024 + lane * 16;   // byte offset in 8KB tile
        const int r = off >> 6;
        const int c = (off >> 4) & 3;
        const int csw = (c ^ (r & 3)) << 3;
        gload_lds16(A + (size_t)(m0 + r) * KDIM + csw,
                    smem + i * 4096 + wid * 1024);
        gload_lds16(Bm + (size_t)(n0 + r) * KDIM + csw,
                    smem + 16384 + i * 4096 + wid * 1024);
    }

    #pragma unroll 1
    for (int s = 0; s < KDIM / 32; ++s) {
        const int cb = s & 1;
        if (s + 1 < KDIM / 32) {
            const int kt = (s + 1) * 32;
            #pragma unroll
            for (int i = 0; i < 2; ++i) {
                const int off = i * 4096 + wid * 1024 + lane * 16;
                const int r = off >> 6;
                const int c = (off >> 4) & 3;
                const int csw = (c ^ (r & 3)) << 3;
                gload_lds16(A + (size_t)(m0 + r) * KDIM + kt + csw,
                            smem + (cb ^ 1) * 8192 + i * 4096 + wid * 1024);
                gload_lds16(Bm + (size_t)(n0 + r) * KDIM + kt + csw,
                            smem + 16384 + (cb ^ 1) * 8192 + i * 4096 + wid * 1024);
            }
            VMCNT(4);           // own stage(s) retired; stage(s+1)'s 4 in flight
        } else {
            VMCNT(0);           // last step: drain everything
        }
        BARRIER();              // all waves' stage(s) visible

        short8 af[4], bf[4];
        #pragma unroll
        for (int mi = 0; mi < 4; ++mi) {
            int row = wr + mi * 16 + lr;
            int ch = lk ^ (row & 3);
            af[mi] = *(const short8*)(smem + cb * 8192 + row * 64 + ch * 16);
        }
        #pragma unroll
        for (int ni = 0; ni < 4; ++ni) {
            int row = wc + ni * 16 + lr;
            int ch = lk ^ (row & 3);
            bf[ni] = *(const short8*)(smem + 16384 + cb * 8192 + row * 64 + ch * 16);
        }
        #pragma unroll
        for (int mi = 0; mi < 4; ++mi)
            #pragma unroll
            for (int ni = 0; ni < 4; ++ni)
                acc[mi][ni] = __builtin_amdgcn_mfma_f32_16x16x32_bf16(
                    af[mi], bf[ni], acc[mi][ni], 0, 0, 0);

        BARRIER();              // all waves done reading buf[cb] -> may be overwritten
    }

    // epilogue: D layout col=lane&15, row=(lane>>4)*4+j  [m89-verified]
    if (MODE == 0) {
        const int seg = n0 / 1536;
        const int nl0 = n0 - seg * 1536;
        if (seg < 2) {
            unsigned short* op = (seg == 0) ? oQ : oK;
            const float* bp = (seg == 0) ? biasq : biask;
            #pragma unroll
            for (int mi = 0; mi < 4; ++mi)
                #pragma unroll
                for (int ni = 0; ni < 4; ++ni)
                    #pragma unroll
                    for (int j = 0; j < 4; ++j) {
                        int row = m0 + wr + mi * 16 + lk * 4 + j;
                        int col = nl0 + wc + ni * 16 + lr;
                        op[(size_t)row * 1536 + col] = f2bf(acc[mi][ni][j] + bp[col]);
                    }
        } else {
            // V segment: transpose through the dead staging LDS into Vt[bh][d][s].
            // Tile = exactly one head (nl0 mult of 128) and one batch (m0 mult of 128).
            // LDS layout: V[d][s] bf16 at  d*256 + (((s>>3)^(d&15))<<4) + (s&7)*2
            // (chunk-XOR swizzle: transposed scalar writes 2-way conflict-free,
            //  16B chunk reads retrieve s-contiguous data).
            #pragma unroll
            for (int mi = 0; mi < 4; ++mi)
                #pragma unroll
                for (int ni = 0; ni < 4; ++ni)
                    #pragma unroll
                    for (int j = 0; j < 4; ++j) {
                        int sl = wr + mi * 16 + lk * 4 + j;        // token within tile
                        int dl = wc + ni * 16 + lr;                // head-dim within tile
                        unsigned short val = f2bf(acc[mi][ni][j] + biasv[nl0 + dl]);
                        *(unsigned short*)(smem + dl * 256 +
                            ((((sl >> 3) ^ (dl & 15))) << 4) + (sl & 7) * 2) = val;
                    }
            BARRIER();
            const int h = nl0 >> 7;              // 0..11
            const int bb = m0 >> 11;             // batch
            const int sseq0 = m0 & 2047;
            const int bh = bb * HQ + h;
            #pragma unroll
            for (int p = 0; p < 8; ++p) {
                int d = wid * 32 + p * 4 + lk;   // 0..127, each exactly once
                int sc = lr;                     // 16B s-chunk 0..15
                u16x8 v = *(const u16x8*)(smem + d * 256 + ((sc ^ (d & 15)) << 4));
                *(u16x8*)(oV + (size_t)(bh * HDQ + d) * SQ + sseq0 + sc * 8) = v;
            }
        }
    } else {
        #pragma unroll
        for (int mi = 0; mi < 4; ++mi)
            #pragma unroll
            for (int ni = 0; ni < 4; ++ni)
                #pragma unroll
                for (int j = 0; j < 4; ++j) {
                    int row = m0 + wr + mi * 16 + lk * 4 + j;
                    int col = n0 + wc + ni * 16 + lr;
                    oF[(size_t)row * 1536 + col] = acc[mi][ni][j] + biaso[col];
                }
    }
}

// ---------------------------------------------------------------- RMSNorm (full row) + RoPE, in place
// grid (4096, 2): y=0 -> (Q, gq), y=1 -> (K, gk)
__global__ __launch_bounds__(256)
void rmsnorm_rope(unsigned short* __restrict__ Qb,
                  unsigned short* __restrict__ Kb,
                  const float* __restrict__ gq,
                  const float* __restrict__ gk,
                  const float* __restrict__ freqs)
{
    unsigned short* T = blockIdx.y ? Kb : Qb;
    const float* g = blockIdx.y ? gk : gq;
    const int token = blockIdx.x;          // 0..4095
    const int s = token & (SQ - 1);
    unsigned int* row = (unsigned int*)(T + (size_t)token * DIMQ);
    const int t = threadIdx.x;
    const int lane = t & 63, wid = t >> 6;

    float pr[3], pi[3];
    float ss = 0.f;
    #pragma unroll
    for (int q = 0; q < 3; ++q) {
        unsigned int v = row[t + q * 256];
        float a = bf2f(v & 0xffffu);
        float b = bf2f(v >> 16);
        pr[q] = a; pi[q] = b;
        ss += a * a + b * b;
    }
    ss += __shfl_xor(ss, 32); ss += __shfl_xor(ss, 16); ss += __shfl_xor(ss, 8);
    ss += __shfl_xor(ss, 4);  ss += __shfl_xor(ss, 2);  ss += __shfl_xor(ss, 1);
    __shared__ float red[4];
    if (lane == 0) red[wid] = ss;
    __syncthreads();
    float tot = red[0] + red[1] + red[2] + red[3];
    float sc = rsqrtf(tot * (1.0f / 1536.0f) + 1e-6f);

    #pragma unroll
    for (int q = 0; q < 3; ++q) {
        int p = t + q * 256;               // global pair index 0..767
        int ph = p & 63;                   // pair-in-head
        float fr = freqs[s * 128 + ph * 2];
        float fi = freqs[s * 128 + ph * 2 + 1];
        float nr = pr[q] * sc * g[2 * p];
        float ni = pi[q] * sc * g[2 * p + 1];
        float outr = nr * fr - ni * fi;
        float outi = nr * fi + ni * fr;
        row[p] = (unsigned int)f2bf(outr) | ((unsigned int)f2bf(outi) << 16);
    }
}

// ---------------------------------------------------------------- flash attention
// EXACT R5 kernel (measured 121.3 us, 104 VGPR, passed): 1 wave per block,
// 32 q-rows, KVBLK=32, NO barriers (wave-private LDS). K double-buffered
// (2x8KB DMA) + V single (8KB, issued early); two counted vmcnts per iter (T4).
// Swapped QK^T = mfma(K,Q), lane-local online softmax, P via cvt_pk +
// shfl_xor(32) + select, PV computes O^T = mfma(V^T, P^T).
// Grid 1536 = 6 blocks/CU exactly; LDS 24KB -> 6 resident.
// NOTE (R11 post-mortem): adding s_setprio around the MFMA clusters bloated
// VGPR 104->140 and halved occupancy -> attn 121->180 us. Do not re-add.
__global__ __launch_bounds__(64, 2)
void attn(const unsigned short* __restrict__ Q,
          const unsigned short* __restrict__ Kb,
          const unsigned short* __restrict__ Vt,
          unsigned short* __restrict__ Ao)
{
    __shared__ char smem[24576];
    char* Kl0 = smem;            // [32 kv][128 k] bf16, 256B rows, XOR-swizzled chunks
    char* Kl1 = smem + 8192;
    char* Vl  = smem + 16384;    // [128 d][32 kv] bf16, 64B rows, XOR-swizzled

    // XCD remap: 8 XCDs x 3 heads x 64 q-blocks (3MB K/V per XCD fits its L2)
    const int fid = blockIdx.x;             // 0..1535
    const int xcd = fid & 7;
    const int slot = fid >> 3;              // 0..191
    const int bh = xcd * 3 + (slot >> 6);   // 0..23
    const int sblk = slot & 63;
    const int b = bh / HQ, h = bh % HQ;
    const int s0 = sblk * 32;

    const int lane = threadIdx.x;
    const int l31 = lane & 31, hi = lane >> 5;
    const float CE = 0.12751879f;           // (1/sqrt(128)) * log2(e)
    const float THR = 90.5f;                // defer-max threshold, raw-score units

    const unsigned short* Kbase = Kb + (size_t)(b * SQ) * DIMQ + h * HDQ;
    const unsigned short* Vbase = Vt + (size_t)(bh * HDQ) * SQ;

    // Q fragments (B-operand: col q = l31, k = kc*16 + hi*8 + e)
    short8 qf[8];
    {
        const unsigned short* qp = Q + (size_t)(b * SQ + s0 + l31) * DIMQ + h * HDQ;
        #pragma unroll
        for (int kc = 0; kc < 8; ++kc)
            qf[kc] = *(const short8*)(qp + kc * 16 + hi * 8);
    }
    MEMFENCE();                 // keep Q loads before the first DMA
    // prologue: K(0) -> Kl0
    #pragma unroll
    for (int i = 0; i < 8; ++i) {
        const int off = i * 1024 + lane * 16;
        int r = off >> 8, c = (off >> 4) & 15;
        gload_lds16(Kbase + (size_t)r * DIMQ + ((c ^ (r & 7)) << 3), Kl0 + i * 1024);
    }
    VMCNT(8);                   // Q settled; K(0)'s 8 DMAs in flight

    char* kcur = Kl0;
    char* knxt = Kl1;
    float mrun = -1e30f, lsum = 0.f, nm = 1e30f;   // nm = -mrun*CE
    f32x16 oacc[4] = {};        // O^T: col q = l31, row d = dt*32 + crow(r,hi)

    #pragma unroll 1
    for (int kv0 = 0; kv0 < SQ; kv0 += 32) {
        // issue V(t): [128 d][32 kv], rows 64B = 4 chunks; swz c ^ ((r>>1)&3)
        #pragma unroll
        for (int i = 0; i < 8; ++i) {
            const int off = i * 1024 + lane * 16;
            int r = off >> 6, c = (off >> 4) & 3;
            gload_lds16(Vbase + (size_t)r * SQ + kv0 + ((c ^ ((r >> 1) & 3)) << 3),
                        Vl + i * 1024);
        }
        MEMFENCE();
        // issue K(t+1) (clamped in-bounds on last iter; dup write never read)
        const int kvn = (kv0 + 32 < SQ) ? kv0 + 32 : kv0;
        #pragma unroll
        for (int i = 0; i < 8; ++i) {
            const int off = i * 1024 + lane * 16;
            int r = off >> 8, c = (off >> 4) & 15;
            gload_lds16(Kbase + (size_t)(kvn + r) * DIMQ + ((c ^ (r & 7)) << 3),
                        knxt + i * 1024);
        }

        VMCNT(16);              // K(t) landed; V(t)+K(t+1) still in flight

        // ---- S^T = K * Q^T, two independent 4-chains
        f32x16 sa = {}, sb = {};
        const int rb = l31 * 256;
        const int rx = l31 & 7;
        #pragma unroll
        for (int kc = 0; kc < 4; ++kc) {
            short8 kf = *(const short8*)(kcur + rb + (((kc * 2 + hi) ^ rx) << 4));
            sa = __builtin_amdgcn_mfma_f32_32x32x16_bf16(kf, qf[kc], sa, 0, 0, 0);
        }
        #pragma unroll
        for (int kc = 4; kc < 8; ++kc) {
            short8 kf = *(const short8*)(kcur + rb + (((kc * 2 + hi) ^ rx) << 4));
            sb = __builtin_amdgcn_mfma_f32_32x32x16_bf16(kf, qf[kc], sb, 0, 0, 0);
        }
        f32x16 s;
        #pragma unroll
        for (int r = 0; r < 16; ++r) s[r] = sa[r] + sb[r];

        // ---- online softmax (lane-local; partner lane^32 holds the other 16 kv)
        float mt[8];
        #pragma unroll
        for (int r = 0; r < 8; ++r) mt[r] = fmaxf(s[r], s[r + 8]);
        #pragma unroll
        for (int st = 4; st > 0; st >>= 1)
            #pragma unroll
            for (int r = 0; r < 4; ++r)
                if (r < st) mt[r] = fmaxf(mt[r], mt[r + st]);
        float tm = fmaxf(mt[0], __shfl_xor(mt[0], 32));
        if (!__all(tm <= mrun + THR)) {     // defer-max (T13)
            float mnew = fmaxf(mrun, tm);
            float al = __builtin_amdgcn_exp2f((mrun - mnew) * CE);
            lsum *= al;
            #pragma unroll
            for (int dt = 0; dt < 4; ++dt)
                #pragma unroll
                for (int r = 0; r < 16; ++r) oacc[dt][r] *= al;
            mrun = mnew;
            nm = -mrun * CE;
        }
        float rs = 0.f;
        #pragma unroll
        for (int r = 0; r < 16; ++r) {
            float p = __builtin_amdgcn_exp2f(__builtin_fmaf(s[r], CE, nm));
            s[r] = p; rs += p;
        }
        rs += __shfl_xor(rs, 32);
        lsum += rs;

        // ---- P -> bf16 B-frags (kv = ks*16 + hi*8 + e per word pair)
        unsigned int A0 = cvtpk_bf16(s[0], s[1]),  A1 = cvtpk_bf16(s[2], s[3]);
        unsigned int B0 = cvtpk_bf16(s[4], s[5]),  B1 = cvtpk_bf16(s[6], s[7]);
        unsigned int C0 = cvtpk_bf16(s[8], s[9]),  C1 = cvtpk_bf16(s[10], s[11]);
        unsigned int D0 = cvtpk_bf16(s[12], s[13]), D1 = cvtpk_bf16(s[14], s[15]);
        unsigned int xA0 = __shfl_xor(A0, 32), xA1 = __shfl_xor(A1, 32);
        unsigned int xB0 = __shfl_xor(B0, 32), xB1 = __shfl_xor(B1, 32);
        unsigned int xC0 = __shfl_xor(C0, 32), xC1 = __shfl_xor(C1, 32);
        unsigned int xD0 = __shfl_xor(D0, 32), xD1 = __shfl_xor(D1, 32);
        union { unsigned int w[4]; short8 v; } pf0, pf1;
        pf0.w[0] = hi ? xB0 : A0;  pf0.w[1] = hi ? xB1 : A1;
        pf0.w[2] = hi ? B0 : xA0;  pf0.w[3] = hi ? B1 : xA1;
        pf1.w[0] = hi ? xD0 : C0;  pf1.w[1] = hi ? xD1 : C1;
        pf1.w[2] = hi ? D0 : xC0;  pf1.w[3] = hi ? D1 : xC1;

        VMCNT(8);               // V(t) landed; K(t+1) still in flight

        // ---- O^T += V^T P^T  (4 independent 2-chains)
        #pragma unroll
        for (int dt = 0; dt < 4; ++dt) {
            const int drow = dt * 32 + l31;
            const int sw = (drow >> 1) & 3;
            short8 v0 = *(const short8*)(Vl + drow * 64 + ((hi ^ sw) << 4));
            short8 v1 = *(const short8*)(Vl + drow * 64 + (((2 + hi) ^ sw) << 4));
            oacc[dt] = __builtin_amdgcn_mfma_f32_32x32x16_bf16(v0, pf0.v, oacc[dt], 0, 0, 0);
            oacc[dt] = __builtin_amdgcn_mfma_f32_32x32x16_bf16(v1, pf1.v, oacc[dt], 0, 0, 0);
        }

        char* tp = kcur; kcur = knxt; knxt = tp;
    }

    // ---- epilogue: normalize, transpose O^T -> O via wave-private swizzled LDS
    // (V region; only K-prefetch DMA is in flight and it targets the K buffers)
    const float rls = 1.0f / lsum;
    char* Ot = Vl;              // [32 q][128 d] bf16, 256B rows, XOR-swizzled
    #pragma unroll
    for (int dt = 0; dt < 4; ++dt)
        #pragma unroll
        for (int rp = 0; rp < 8; ++rp) {
            const int r = 2 * rp;
            float v0 = oacc[dt][r] * rls;
            float v1 = oacc[dt][r + 1] * rls;
            int d = dt * 32 + (r & 3) + 8 * (r >> 2) + 4 * hi;   // even
            unsigned int w = (unsigned int)f2bf(v0) | ((unsigned int)f2bf(v1) << 16);
            int addr = l31 * 256 + (((d >> 3) ^ (l31 & 7)) << 4) + (d & 7) * 2;
            *(unsigned int*)(Ot + addr) = w;
        }
    #pragma unroll
    for (int ii = 0; ii < 8; ++ii) {
        int task = ii * 64 + lane;          // 32 q x 16 chunks
        int q = task >> 4, c = task & 15;
        u16x8 vv = *(const u16x8*)(Ot + q * 256 + ((c ^ (q & 7)) << 4));
        int tok = b * SQ + s0 + q;
        *(u16x8*)(Ao + (size_t)tok * DIMQ + h * HDQ + c * 8) = vv;
    }
}

// ---------------------------------------------------------------- launch
extern "C" void kernel_launch(void* const* d_in, const int* in_sizes, int n_in,
                              void* d_out, int out_size, void* d_ws, size_t ws_size,
                              hipStream_t stream) {
    (void)in_sizes; (void)n_in; (void)out_size; (void)ws_size;
    const float* x     = (const float*)d_in[0];
    const float* freqs = (const float*)d_in[1];
    const float* wq = (const float*)d_in[2];
    const float* bq = (const float*)d_in[3];
    const float* wk = (const float*)d_in[4];
    const float* bk = (const float*)d_in[5];
    const float* wv = (const float*)d_in[6];
    const float* bv = (const float*)d_in[7];
    const float* wo = (const float*)d_in[8];
    const float* bo = (const float*)d_in[9];
    const float* gq = (const float*)d_in[10];
    const float* gk = (const float*)d_in[11];
    float* out = (float*)d_out;

    char* w = (char*)d_ws;
    unsigned short* Xb   = (unsigned short*)(w);               // 4096x1536 bf16
    unsigned short* Wqkv = (unsigned short*)(w + 12582912);    // 4608x1536 bf16
    unsigned short* Wob  = (unsigned short*)(w + 26738688);    // 1536x1536 bf16
    unsigned short* Qb   = (unsigned short*)(w + 31457280);    // 4096x1536 bf16
    unsigned short* Kbuf = (unsigned short*)(w + 44040192);    // 4096x1536 bf16
    unsigned short* Vt   = (unsigned short*)(w + 69206016);    // 24x128x2048 bf16 (attn-ready)
    unsigned short* Ao   = Xb;   // Xb dead after GEMM1 -> reuse for attention out

    cast_all<<<2048, 256, 0, stream>>>(x, wq, wk, wv, wo, Xb, Wqkv, Wob);

    gemm_bt<0><<<dim3(32, 36), 256, 0, stream>>>(
        Xb, Wqkv, Qb, Kbuf, Vt, bq, bk, bv, nullptr, nullptr);

    rmsnorm_rope<<<dim3(4096, 2), 256, 0, stream>>>(Qb, Kbuf, gq, gk, freqs);

    attn<<<1536, 64, 0, stream>>>(Qb, Kbuf, Vt, Ao);

    gemm_bt<1><<<dim3(32, 12), 256, 0, stream>>>(
        Ao, Wob, nullptr, nullptr, nullptr, nullptr, nullptr, nullptr, out, bo);
}